// Round 1
// baseline (3137.260 us; speedup 1.0000x reference)
//
#include <hip/hip_runtime.h>
#include <hip/hip_bf16.h>
#include <math.h>

// Problem constants (fixed by the reference)
#define NN   10000   // nodes
#define EE   160000  // edges
#define WID  256     // node width
#define HIDD 512     // hidden
#define EWID 128     // edge embed width
#define TE   16      // edges per block in fused edge kernel

__device__ __forceinline__ float geluf(float x) {
    // exact (erf) GELU, matches torch nn.GELU default
    return 0.5f * x * (1.0f + erff(x * 0.70710678118654752f));
}

// ---------------- zero agg ----------------
__global__ __launch_bounds__(256) void k_zero(float4* __restrict__ p, int n4) {
    int i = blockIdx.x * 256 + threadIdx.x;
    if (i < n4) p[i] = make_float4(0.f, 0.f, 0.f, 0.f);
}

// ---------------- pre: xx = LN(x @ W_pre + b_pre) ----------------
// 8 rows/block, 256 threads (one output col each). A staged transposed in LDS.
__global__ __launch_bounds__(256) void k_pre(const float* __restrict__ x,
                                             const float* __restrict__ Wp,
                                             const float* __restrict__ bp,
                                             float* __restrict__ xx) {
    __shared__ __align__(16) float xs[WID * 12];   // [i][g], pitch 12 (8 used)
    __shared__ __align__(16) float ot[8 * WID];
    __shared__ float mean_s[8], rstd_s[8];
    int t = threadIdx.x;
    int r0 = blockIdx.x * 8;
    #pragma unroll
    for (int g = 0; g < 8; ++g) {
        int r = r0 + g;
        xs[t * 12 + g] = (r < NN) ? x[r * WID + t] : 0.f;
    }
    __syncthreads();
    float acc[8];
    #pragma unroll
    for (int g = 0; g < 8; ++g) acc[g] = 0.f;
    for (int i = 0; i < WID; ++i) {
        float w = Wp[i * WID + t];            // coalesced, L2-resident (256 KB)
        float4 a0 = *(const float4*)&xs[i * 12];
        float4 a1 = *(const float4*)&xs[i * 12 + 4];
        acc[0] += a0.x * w; acc[1] += a0.y * w; acc[2] += a0.z * w; acc[3] += a0.w * w;
        acc[4] += a1.x * w; acc[5] += a1.y * w; acc[6] += a1.z * w; acc[7] += a1.w * w;
    }
    float bb = bp[t];
    #pragma unroll
    for (int g = 0; g < 8; ++g) ot[g * WID + t] = acc[g] + bb;
    __syncthreads();
    int wave = t >> 6, lane = t & 63;
    for (int r = wave * 2; r < wave * 2 + 2; ++r) {
        float s = 0.f, s2 = 0.f;
        #pragma unroll
        for (int k2 = 0; k2 < 4; ++k2) {
            float v = ot[r * WID + lane + 64 * k2];
            s += v; s2 += v * v;
        }
        #pragma unroll
        for (int off = 32; off >= 1; off >>= 1) {
            s  += __shfl_xor(s,  off, 64);
            s2 += __shfl_xor(s2, off, 64);
        }
        if (lane == 0) {
            float m = s * (1.f / WID);
            float var = s2 * (1.f / WID) - m * m;
            mean_s[r] = m;
            rstd_s[r] = rsqrtf(var + 1e-5f);
        }
    }
    __syncthreads();
    #pragma unroll
    for (int g = 0; g < 8; ++g) {
        int r = r0 + g;
        if (r < NN) xx[r * WID + t] = (ot[g * WID + t] - mean_s[g]) * rstd_s[g];
    }
}

// ---------------- node QKV + msg0: four 256x512 GEMMs off xx ----------------
// 16 rows/block; blockIdx.y in [0,8): 2 col-halves for each of Q,K,V,M0.
__global__ __launch_bounds__(256) void k_qkvm(const float* __restrict__ xx,
    const float* __restrict__ Wq, const float* __restrict__ bq,
    const float* __restrict__ Wk, const float* __restrict__ bk,
    const float* __restrict__ Wv, const float* __restrict__ bv,
    const float* __restrict__ Wm, const float* __restrict__ bm,
    float* __restrict__ XQ, float* __restrict__ XK,
    float* __restrict__ XV, float* __restrict__ M0) {
    __shared__ __align__(16) float xs[WID * 20];   // [i][g], pitch 20 (16 used)
    int t = threadIdx.x;
    int r0 = blockIdx.x * 16;
    int chunk = blockIdx.y;          // 0..7
    int sel = chunk >> 1;
    int col = (chunk & 1) * 256 + t;
    const float* Wsel = sel == 0 ? Wq : sel == 1 ? Wk : sel == 2 ? Wv : Wm;
    const float* bsel = sel == 0 ? bq : sel == 1 ? bk : sel == 2 ? bv : bm;
    float* osel       = sel == 0 ? XQ : sel == 1 ? XK : sel == 2 ? XV : M0;
    #pragma unroll
    for (int g = 0; g < 16; ++g) {
        int r = r0 + g;
        xs[t * 20 + g] = (r < NN) ? xx[r * WID + t] : 0.f;
    }
    __syncthreads();
    float acc[16];
    #pragma unroll
    for (int g = 0; g < 16; ++g) acc[g] = 0.f;
    for (int i = 0; i < WID; ++i) {
        float w = Wsel[i * HIDD + col];
        #pragma unroll
        for (int q4 = 0; q4 < 4; ++q4) {
            float4 a = *(const float4*)&xs[i * 20 + q4 * 4];
            acc[q4 * 4 + 0] += a.x * w; acc[q4 * 4 + 1] += a.y * w;
            acc[q4 * 4 + 2] += a.z * w; acc[q4 * 4 + 3] += a.w * w;
        }
    }
    float bb = bsel[col];
    bool dogelu = (sel == 3);
    #pragma unroll
    for (int g = 0; g < 16; ++g) {
        int r = r0 + g;
        if (r < NN) {
            float v = acc[g] + bb;
            if (dogelu) v = geluf(v);
            osel[r * HIDD + col] = v;
        }
    }
}

// ---------------- fused edge kernel ----------------
// Per block: 16 edges. Build ee tile in LDS, compute R0/R1/R2 via fp32 VALU
// GEMM (K=128) fused with node-Q/K/V gathers, per-head attention, then
// atomicAdd the scaled V into agg[dst]. R (E x 1536) never hits HBM.
__global__ __launch_bounds__(256) void k_edge(
    const int* __restrict__ eidx, const int* __restrict__ eattr,
    const float* __restrict__ eemb,
    const float* __restrict__ emb0, const float* __restrict__ emb1,
    const float* __restrict__ emb2, const float* __restrict__ emb3,
    const float* __restrict__ i0e, const float* __restrict__ i0,
    const float* __restrict__ XQ, const float* __restrict__ XK,
    const float* __restrict__ XV,
    const float* __restrict__ Wr0, const float* __restrict__ br0,
    const float* __restrict__ Wr1, const float* __restrict__ br1,
    const float* __restrict__ Wr2, const float* __restrict__ br2,
    float* __restrict__ agg) {
    __shared__ __align__(16) float ee_t[EWID * 20];        // [i][e] pitch 20
    __shared__ __align__(16) float q_s[TE * 520];
    __shared__ __align__(16) float k_s[TE * 520];
    __shared__ __align__(16) float v_s[TE * 520];
    __shared__ float att_s[TE * 8];
    __shared__ int dst_s[TE], src_s[TE];
    int t = threadIdx.x;
    int e0 = blockIdx.x * TE;
    if (t < TE) {
        src_s[t] = eidx[e0 + t];        // row 0 = j (source)
        dst_s[t] = eidx[EE + e0 + t];   // row 1 = i (target)
    }
    float ev0 = __expf(i0e[0]), ev1 = __expf(i0e[1]),
          ev2 = __expf(i0e[2]), ev3 = __expf(i0e[3]);
    float rs = rsqrtf(ev0 + ev1 + ev2 + ev3);
    float xw0 = ev0 * rs, xw1 = ev1 * rs, xw2 = ev2 * rs, xw3 = ev3 * rs;
    float a_sc = i0[0], a_bi = i0[1];
    float s_e = expf(i0[2]), s_v = expf(i0[3]);
    // ee tile: 16 edges x 128 cols
    #pragma unroll
    for (int k2 = 0; k2 < 8; ++k2) {
        int idx = k2 * 256 + t;
        int e = idx >> 7, c = idx & 127;
        int ed = e0 + e;
        int a0 = eattr[ed * 4 + 0], a1 = eattr[ed * 4 + 1];
        int a2 = eattr[ed * 4 + 2], a3 = eattr[ed * 4 + 3];
        float v = xw0 * emb0[a0 * EWID + c] + xw1 * emb1[a1 * EWID + c]
                + xw2 * emb2[a2 * EWID + c] + xw3 * emb3[a3 * EWID + c];
        ee_t[c * 20 + e] = 0.5f * (v + eemb[ed * EWID + c]);
    }
    __syncthreads();
    for (int part = 0; part < 3; ++part) {
        const float* Wr = part == 0 ? Wr0 : part == 1 ? Wr1 : Wr2;
        const float* br = part == 0 ? br0 : part == 1 ? br1 : br2;
        const float* Xg = part == 0 ? XQ  : part == 1 ? XK  : XV;
        float* outp     = part == 0 ? q_s : part == 1 ? k_s : v_s;
        float s = (part == 2) ? s_v : s_e;
        float acc[32];
        #pragma unroll
        for (int u = 0; u < 32; ++u) acc[u] = 0.f;
        for (int i = 0; i < EWID; ++i) {
            float w0 = Wr[i * HIDD + t];          // L2-resident weights
            float w1 = Wr[i * HIDD + 256 + t];
            #pragma unroll
            for (int q4 = 0; q4 < 4; ++q4) {
                float4 a = *(const float4*)&ee_t[i * 20 + q4 * 4];
                acc[q4 * 4 + 0]      += a.x * w0; acc[q4 * 4 + 1]      += a.y * w0;
                acc[q4 * 4 + 2]      += a.z * w0; acc[q4 * 4 + 3]      += a.w * w0;
                acc[16 + q4 * 4 + 0] += a.x * w1; acc[16 + q4 * 4 + 1] += a.y * w1;
                acc[16 + q4 * 4 + 2] += a.z * w1; acc[16 + q4 * 4 + 3] += a.w * w1;
            }
        }
        float bb0 = br[t] * s, bb1 = br[256 + t] * s;
        const int* gidx = (part == 0) ? dst_s : src_s;
        #pragma unroll
        for (int e = 0; e < TE; ++e) {
            int nrow = gidx[e];
            float v0 = Xg[nrow * HIDD + t]       + s * acc[e]      + bb0;
            float v1 = Xg[nrow * HIDD + 256 + t] + s * acc[16 + e] + bb1;
            if (part == 2) { v0 = geluf(v0); v1 = geluf(v1); }
            outp[e * 520 + t] = v0;
            outp[e * 520 + 256 + t] = v1;
        }
    }
    __syncthreads();
    // attention: (e,h,dc) = 16 x 8 x 2 over 256 threads; 32-dim partial dots
    {
        int e = t & 15, hh = t >> 4;
        int h = hh >> 1, dc = hh & 1;
        const float* qp = &q_s[e * 520 + h * 64 + dc * 32];
        const float* kp = &k_s[e * 520 + h * 64 + dc * 32];
        float s = 0.f;
        #pragma unroll
        for (int d = 0; d < 32; ++d) s += qp[d] * kp[d];
        s += __shfl_xor(s, 16, 64);   // combine the two 32-dim halves
        if (dc == 0) {
            float dot = s * 0.125f;   // / sqrt(64)
            att_s[e * 8 + h] = expf(dot * a_sc + a_bi);
        }
    }
    __syncthreads();
    // msg = v * att(head), scatter-add to agg[dst]
    for (int k2 = 0; k2 < 32; ++k2) {
        int idx = k2 * 256 + t;
        int e = idx >> 9, c = idx & 511;
        float m = v_s[e * 520 + c] * att_s[e * 8 + (c >> 6)];
        atomicAdd(&agg[dst_s[e] * HIDD + c], m);
    }
}

// ---------------- post: out = x + (M0 + agg) @ W_post + b_post ----------------
__global__ __launch_bounds__(256) void k_post(const float* __restrict__ x,
    const float* __restrict__ M0, const float* __restrict__ agg,
    const float* __restrict__ Wp, const float* __restrict__ bp,
    float* __restrict__ out) {
    __shared__ __align__(16) float xs[HIDD * 20];  // [i][g] pitch 20 (16 used)
    int t = threadIdx.x;
    int r0 = blockIdx.x * 16;
    #pragma unroll
    for (int g = 0; g < 16; ++g) {
        int r = r0 + g;
        for (int h = 0; h < 2; ++h) {
            int i = h * 256 + t;
            xs[i * 20 + g] = (r < NN) ? (M0[r * HIDD + i] + agg[r * HIDD + i]) : 0.f;
        }
    }
    __syncthreads();
    float acc[16];
    #pragma unroll
    for (int g = 0; g < 16; ++g) acc[g] = 0.f;
    for (int i = 0; i < HIDD; ++i) {
        float w = Wp[i * WID + t];
        #pragma unroll
        for (int q4 = 0; q4 < 4; ++q4) {
            float4 a = *(const float4*)&xs[i * 20 + q4 * 4];
            acc[q4 * 4 + 0] += a.x * w; acc[q4 * 4 + 1] += a.y * w;
            acc[q4 * 4 + 2] += a.z * w; acc[q4 * 4 + 3] += a.w * w;
        }
    }
    float bb = bp[t];
    #pragma unroll
    for (int g = 0; g < 16; ++g) {
        int r = r0 + g;
        if (r < NN) out[r * WID + t] = x[r * WID + t] + acc[g] + bb;
    }
}

extern "C" void kernel_launch(void* const* d_in, const int* in_sizes, int n_in,
                              void* d_out, int out_size, void* d_ws, size_t ws_size,
                              hipStream_t stream) {
    const float* x     = (const float*)d_in[0];
    const int*   eidx  = (const int*)  d_in[1];
    const int*   eattr = (const int*)  d_in[2];
    const float* eemb  = (const float*)d_in[3];
    const float* emb0  = (const float*)d_in[4];
    const float* emb1  = (const float*)d_in[5];
    const float* emb2  = (const float*)d_in[6];
    const float* emb3  = (const float*)d_in[7];
    const float* i0e   = (const float*)d_in[8];
    const float* i0    = (const float*)d_in[9];
    const float* Wpre  = (const float*)d_in[10];
    const float* bpre  = (const float*)d_in[11];
    const float* Wm    = (const float*)d_in[12];
    const float* bm    = (const float*)d_in[13];
    const float* Wq    = (const float*)d_in[14];
    const float* bq    = (const float*)d_in[15];
    const float* Wk    = (const float*)d_in[16];
    const float* bk    = (const float*)d_in[17];
    const float* Wv    = (const float*)d_in[18];
    const float* bv    = (const float*)d_in[19];
    const float* Wr0   = (const float*)d_in[20];
    const float* br0   = (const float*)d_in[21];
    const float* Wr1   = (const float*)d_in[22];
    const float* br1   = (const float*)d_in[23];
    const float* Wr2   = (const float*)d_in[24];
    const float* br2   = (const float*)d_in[25];
    const float* Wpost = (const float*)d_in[26];
    const float* bpost = (const float*)d_in[27];

    float* ws  = (float*)d_ws;
    float* xx  = ws;                         // N*256   = 2,560,000
    float* XQ  = ws + 2560000;               // N*512   = 5,120,000
    float* XK  = ws + 7680000;
    float* XV  = ws + 12800000;
    float* M0  = ws + 17920000;
    float* agg = ws + 23040000;              // N*512
    // total 28,160,000 floats = 112.6 MB

    k_zero<<<5000, 256, 0, stream>>>((float4*)agg, NN * HIDD / 4);
    k_pre<<<NN / 8, 256, 0, stream>>>(x, Wpre, bpre, xx);
    k_qkvm<<<dim3(NN / 16, 8), 256, 0, stream>>>(xx, Wq, bq, Wk, bk, Wv, bv, Wm, bm,
                                                 XQ, XK, XV, M0);
    k_edge<<<EE / TE, 256, 0, stream>>>(eidx, eattr, eemb, emb0, emb1, emb2, emb3,
                                        i0e, i0, XQ, XK, XV,
                                        Wr0, br0, Wr1, br1, Wr2, br2, agg);
    k_post<<<NN / 16, 256, 0, stream>>>(x, M0, agg, Wpost, bpost, (float*)d_out);
}

// Round 2
// 2044.270 us; speedup vs baseline: 1.5347x; 1.5347x over previous
//
#include <hip/hip_runtime.h>
#include <hip/hip_bf16.h>
#include <math.h>

// Problem constants (fixed by the reference)
#define NN   10000   // nodes
#define EE   160000  // edges
#define WID  256     // node width
#define HIDD 512     // hidden
#define EWID 128     // edge embed width
#define TE   16      // edges per block in fused edge kernel

__device__ __forceinline__ float geluf(float x) {
    // exact (erf) GELU, matches torch nn.GELU default
    return 0.5f * x * (1.0f + erff(x * 0.70710678118654752f));
}

// ---------------- zero agg ----------------
__global__ __launch_bounds__(256) void k_zero(float4* __restrict__ p, int n4) {
    int i = blockIdx.x * 256 + threadIdx.x;
    if (i < n4) p[i] = make_float4(0.f, 0.f, 0.f, 0.f);
}

// ---------------- pre: xx = LN(x @ W_pre + b_pre) ----------------
__global__ __launch_bounds__(256) void k_pre(const float* __restrict__ x,
                                             const float* __restrict__ Wp,
                                             const float* __restrict__ bp,
                                             float* __restrict__ xx) {
    __shared__ __align__(16) float xs[WID * 12];   // [i][g], pitch 12 (8 used)
    __shared__ __align__(16) float ot[8 * WID];
    __shared__ float mean_s[8], rstd_s[8];
    int t = threadIdx.x;
    int r0 = blockIdx.x * 8;
    #pragma unroll
    for (int g = 0; g < 8; ++g) {
        int r = r0 + g;
        xs[t * 12 + g] = (r < NN) ? x[r * WID + t] : 0.f;
    }
    __syncthreads();
    float acc[8];
    #pragma unroll
    for (int g = 0; g < 8; ++g) acc[g] = 0.f;
    for (int i = 0; i < WID; ++i) {
        float w = Wp[i * WID + t];
        float4 a0 = *(const float4*)&xs[i * 12];
        float4 a1 = *(const float4*)&xs[i * 12 + 4];
        acc[0] += a0.x * w; acc[1] += a0.y * w; acc[2] += a0.z * w; acc[3] += a0.w * w;
        acc[4] += a1.x * w; acc[5] += a1.y * w; acc[6] += a1.z * w; acc[7] += a1.w * w;
    }
    float bb = bp[t];
    #pragma unroll
    for (int g = 0; g < 8; ++g) ot[g * WID + t] = acc[g] + bb;
    __syncthreads();
    int wave = t >> 6, lane = t & 63;
    for (int r = wave * 2; r < wave * 2 + 2; ++r) {
        float s = 0.f, s2 = 0.f;
        #pragma unroll
        for (int k2 = 0; k2 < 4; ++k2) {
            float v = ot[r * WID + lane + 64 * k2];
            s += v; s2 += v * v;
        }
        #pragma unroll
        for (int off = 32; off >= 1; off >>= 1) {
            s  += __shfl_xor(s,  off, 64);
            s2 += __shfl_xor(s2, off, 64);
        }
        if (lane == 0) {
            float m = s * (1.f / WID);
            float var = s2 * (1.f / WID) - m * m;
            mean_s[r] = m;
            rstd_s[r] = rsqrtf(var + 1e-5f);
        }
    }
    __syncthreads();
    #pragma unroll
    for (int g = 0; g < 8; ++g) {
        int r = r0 + g;
        if (r < NN) xx[r * WID + t] = (ot[g * WID + t] - mean_s[g]) * rstd_s[g];
    }
}

// ---------------- node QKV + msg0: four 256x512 GEMMs off xx ----------------
__global__ __launch_bounds__(256) void k_qkvm(const float* __restrict__ xx,
    const float* __restrict__ Wq, const float* __restrict__ bq,
    const float* __restrict__ Wk, const float* __restrict__ bk,
    const float* __restrict__ Wv, const float* __restrict__ bv,
    const float* __restrict__ Wm, const float* __restrict__ bm,
    float* __restrict__ XQ, float* __restrict__ XK,
    float* __restrict__ XV, float* __restrict__ M0) {
    __shared__ __align__(16) float xs[WID * 20];   // [i][g], pitch 20 (16 used)
    int t = threadIdx.x;
    int r0 = blockIdx.x * 16;
    int chunk = blockIdx.y;          // 0..7
    int sel = chunk >> 1;
    int col = (chunk & 1) * 256 + t;
    const float* Wsel = sel == 0 ? Wq : sel == 1 ? Wk : sel == 2 ? Wv : Wm;
    const float* bsel = sel == 0 ? bq : sel == 1 ? bk : sel == 2 ? bv : bm;
    float* osel       = sel == 0 ? XQ : sel == 1 ? XK : sel == 2 ? XV : M0;
    #pragma unroll
    for (int g = 0; g < 16; ++g) {
        int r = r0 + g;
        xs[t * 20 + g] = (r < NN) ? xx[r * WID + t] : 0.f;
    }
    __syncthreads();
    float acc[16];
    #pragma unroll
    for (int g = 0; g < 16; ++g) acc[g] = 0.f;
    for (int i = 0; i < WID; ++i) {
        float w = Wsel[i * HIDD + col];
        #pragma unroll
        for (int q4 = 0; q4 < 4; ++q4) {
            float4 a = *(const float4*)&xs[i * 20 + q4 * 4];
            acc[q4 * 4 + 0] += a.x * w; acc[q4 * 4 + 1] += a.y * w;
            acc[q4 * 4 + 2] += a.z * w; acc[q4 * 4 + 3] += a.w * w;
        }
    }
    float bb = bsel[col];
    bool dogelu = (sel == 3);
    #pragma unroll
    for (int g = 0; g < 16; ++g) {
        int r = r0 + g;
        if (r < NN) {
            float v = acc[g] + bb;
            if (dogelu) v = geluf(v);
            osel[r * HIDD + col] = v;
        }
    }
}

// ---------------- fused edge kernel (register-resident q/k/v) ----------------
// 16 edges/block, 256 threads. Thread t owns output cols t and t+256.
// Head mapping: col t -> head t>>6 == wave index w; col t+256 -> head w+4.
// So per-head attention dots are wave-internal butterfly reductions, and each
// lane ends up with exactly the att weights needed to scale its own v cols.
// LDS holds only the ee tile (~10 KB) -> occupancy VGPR-limited, not LDS-limited.
#define RGEMM(WPTR, ACC)                                                        \
    {                                                                           \
        _Pragma("unroll 4")                                                     \
        for (int i = 0; i < EWID; ++i) {                                        \
            float w0 = WPTR[i * HIDD + t];                                      \
            float w1 = WPTR[i * HIDD + 256 + t];                                \
            _Pragma("unroll")                                                   \
            for (int q4 = 0; q4 < 4; ++q4) {                                    \
                float4 a = *(const float4*)&ee_t[i * 20 + q4 * 4];              \
                ACC[q4*4+0]    += a.x * w0; ACC[q4*4+1]    += a.y * w0;         \
                ACC[q4*4+2]    += a.z * w0; ACC[q4*4+3]    += a.w * w0;         \
                ACC[16+q4*4+0] += a.x * w1; ACC[16+q4*4+1] += a.y * w1;         \
                ACC[16+q4*4+2] += a.z * w1; ACC[16+q4*4+3] += a.w * w1;         \
            }                                                                   \
        }                                                                       \
    }

__global__ __launch_bounds__(256) void k_edge(
    const int* __restrict__ eidx, const int* __restrict__ eattr,
    const float* __restrict__ eemb,
    const float* __restrict__ emb0, const float* __restrict__ emb1,
    const float* __restrict__ emb2, const float* __restrict__ emb3,
    const float* __restrict__ i0e, const float* __restrict__ i0,
    const float* __restrict__ XQ, const float* __restrict__ XK,
    const float* __restrict__ XV,
    const float* __restrict__ Wr0, const float* __restrict__ br0,
    const float* __restrict__ Wr1, const float* __restrict__ br1,
    const float* __restrict__ Wr2, const float* __restrict__ br2,
    float* __restrict__ agg) {
    __shared__ __align__(16) float ee_t[EWID * 20];        // [i][e] pitch 20
    __shared__ int dst_s[TE], src_s[TE];
    int t = threadIdx.x;
    int e0 = blockIdx.x * TE;
    if (t < TE) {
        src_s[t] = eidx[e0 + t];        // row 0 = j (source)
        dst_s[t] = eidx[EE + e0 + t];   // row 1 = i (target)
    }
    float ev0 = __expf(i0e[0]), ev1 = __expf(i0e[1]),
          ev2 = __expf(i0e[2]), ev3 = __expf(i0e[3]);
    float rs = rsqrtf(ev0 + ev1 + ev2 + ev3);
    float xw0 = ev0 * rs, xw1 = ev1 * rs, xw2 = ev2 * rs, xw3 = ev3 * rs;
    float a_sc = i0[0], a_bi = i0[1];
    float s_e = expf(i0[2]), s_v = expf(i0[3]);
    float c_sc = 0.125f * a_sc;                 // fold 1/sqrt(64) into scale
    // ee tile: 16 edges x 128 cols
    #pragma unroll
    for (int k2 = 0; k2 < 8; ++k2) {
        int idx = k2 * 256 + t;
        int e = idx >> 7, c = idx & 127;
        int ed = e0 + e;
        int a0 = eattr[ed * 4 + 0], a1 = eattr[ed * 4 + 1];
        int a2 = eattr[ed * 4 + 2], a3 = eattr[ed * 4 + 3];
        float v = xw0 * emb0[a0 * EWID + c] + xw1 * emb1[a1 * EWID + c]
                + xw2 * emb2[a2 * EWID + c] + xw3 * emb3[a3 * EWID + c];
        ee_t[c * 20 + e] = 0.5f * (v + eemb[ed * EWID + c]);
    }
    __syncthreads();

    // ---- Q ----
    float accq[32];
    #pragma unroll
    for (int u = 0; u < 32; ++u) accq[u] = 0.f;
    RGEMM(Wr0, accq);
    float q0[TE], q1[TE];
    {
        float bb0 = br0[t] * s_e, bb1 = br0[256 + t] * s_e;
        #pragma unroll
        for (int e = 0; e < TE; ++e) {
            int n = dst_s[e];
            q0[e] = XQ[n * HIDD + t]       + s_e * accq[e]      + bb0;
            q1[e] = XQ[n * HIDD + 256 + t] + s_e * accq[16 + e] + bb1;
        }
    }
    // ---- K ----
    float acck[32];
    #pragma unroll
    for (int u = 0; u < 32; ++u) acck[u] = 0.f;
    RGEMM(Wr1, acck);
    float att0[TE], att1[TE];
    {
        float bb0 = br1[t] * s_e, bb1 = br1[256 + t] * s_e;
        #pragma unroll
        for (int e = 0; e < TE; ++e) {
            int n = src_s[e];
            float k0 = XK[n * HIDD + t]       + s_e * acck[e]      + bb0;
            float k1 = XK[n * HIDD + 256 + t] + s_e * acck[16 + e] + bb1;
            float d0 = q0[e] * k0;
            float d1 = q1[e] * k1;
            #pragma unroll
            for (int off = 32; off >= 1; off >>= 1) {
                d0 += __shfl_xor(d0, off, 64);
                d1 += __shfl_xor(d1, off, 64);
            }
            att0[e] = expf(d0 * c_sc + a_bi);
            att1[e] = expf(d1 * c_sc + a_bi);
        }
    }
    // ---- V + scatter ----
    float accv[32];
    #pragma unroll
    for (int u = 0; u < 32; ++u) accv[u] = 0.f;
    RGEMM(Wr2, accv);
    {
        float bb0 = br2[t] * s_v, bb1 = br2[256 + t] * s_v;
        #pragma unroll
        for (int e = 0; e < TE; ++e) {
            int ns = src_s[e], nd = dst_s[e];
            float v0 = geluf(XV[ns * HIDD + t]       + s_v * accv[e]      + bb0);
            float v1 = geluf(XV[ns * HIDD + 256 + t] + s_v * accv[16 + e] + bb1);
            atomicAdd(&agg[nd * HIDD + t],       v0 * att0[e]);
            atomicAdd(&agg[nd * HIDD + 256 + t], v1 * att1[e]);
        }
    }
}

// ---------------- post: out = x + (M0 + agg) @ W_post + b_post ----------------
__global__ __launch_bounds__(256) void k_post(const float* __restrict__ x,
    const float* __restrict__ M0, const float* __restrict__ agg,
    const float* __restrict__ Wp, const float* __restrict__ bp,
    float* __restrict__ out) {
    __shared__ __align__(16) float xs[HIDD * 20];  // [i][g] pitch 20 (16 used)
    int t = threadIdx.x;
    int r0 = blockIdx.x * 16;
    #pragma unroll
    for (int g = 0; g < 16; ++g) {
        int r = r0 + g;
        for (int h = 0; h < 2; ++h) {
            int i = h * 256 + t;
            xs[i * 20 + g] = (r < NN) ? (M0[r * HIDD + i] + agg[r * HIDD + i]) : 0.f;
        }
    }
    __syncthreads();
    float acc[16];
    #pragma unroll
    for (int g = 0; g < 16; ++g) acc[g] = 0.f;
    for (int i = 0; i < HIDD; ++i) {
        float w = Wp[i * WID + t];
        #pragma unroll
        for (int q4 = 0; q4 < 4; ++q4) {
            float4 a = *(const float4*)&xs[i * 20 + q4 * 4];
            acc[q4 * 4 + 0] += a.x * w; acc[q4 * 4 + 1] += a.y * w;
            acc[q4 * 4 + 2] += a.z * w; acc[q4 * 4 + 3] += a.w * w;
        }
    }
    float bb = bp[t];
    #pragma unroll
    for (int g = 0; g < 16; ++g) {
        int r = r0 + g;
        if (r < NN) out[r * WID + t] = x[r * WID + t] + acc[g] + bb;
    }
}

extern "C" void kernel_launch(void* const* d_in, const int* in_sizes, int n_in,
                              void* d_out, int out_size, void* d_ws, size_t ws_size,
                              hipStream_t stream) {
    const float* x     = (const float*)d_in[0];
    const int*   eidx  = (const int*)  d_in[1];
    const int*   eattr = (const int*)  d_in[2];
    const float* eemb  = (const float*)d_in[3];
    const float* emb0  = (const float*)d_in[4];
    const float* emb1  = (const float*)d_in[5];
    const float* emb2  = (const float*)d_in[6];
    const float* emb3  = (const float*)d_in[7];
    const float* i0e   = (const float*)d_in[8];
    const float* i0    = (const float*)d_in[9];
    const float* Wpre  = (const float*)d_in[10];
    const float* bpre  = (const float*)d_in[11];
    const float* Wm    = (const float*)d_in[12];
    const float* bm    = (const float*)d_in[13];
    const float* Wq    = (const float*)d_in[14];
    const float* bq    = (const float*)d_in[15];
    const float* Wk    = (const float*)d_in[16];
    const float* bk    = (const float*)d_in[17];
    const float* Wv    = (const float*)d_in[18];
    const float* bv    = (const float*)d_in[19];
    const float* Wr0   = (const float*)d_in[20];
    const float* br0   = (const float*)d_in[21];
    const float* Wr1   = (const float*)d_in[22];
    const float* br1   = (const float*)d_in[23];
    const float* Wr2   = (const float*)d_in[24];
    const float* br2   = (const float*)d_in[25];
    const float* Wpost = (const float*)d_in[26];
    const float* bpost = (const float*)d_in[27];

    float* ws  = (float*)d_ws;
    float* xx  = ws;                         // N*256   = 2,560,000
    float* XQ  = ws + 2560000;               // N*512   = 5,120,000
    float* XK  = ws + 7680000;
    float* XV  = ws + 12800000;
    float* M0  = ws + 17920000;
    float* agg = ws + 23040000;              // N*512
    // total 28,160,000 floats = 112.6 MB

    k_zero<<<5000, 256, 0, stream>>>((float4*)agg, NN * HIDD / 4);
    k_pre<<<NN / 8, 256, 0, stream>>>(x, Wpre, bpre, xx);
    k_qkvm<<<dim3(NN / 16, 8), 256, 0, stream>>>(xx, Wq, bq, Wk, bk, Wv, bv, Wm, bm,
                                                 XQ, XK, XV, M0);
    k_edge<<<EE / TE, 256, 0, stream>>>(eidx, eattr, eemb, emb0, emb1, emb2, emb3,
                                        i0e, i0, XQ, XK, XV,
                                        Wr0, br0, Wr1, br1, Wr2, br2, agg);
    k_post<<<NN / 16, 256, 0, stream>>>(x, M0, agg, Wpost, bpost, (float*)d_out);
}

// Round 3
// 1411.855 us; speedup vs baseline: 2.2221x; 1.4479x over previous
//
#include <hip/hip_runtime.h>
#include <hip/hip_bf16.h>
#include <math.h>

// Problem constants (fixed by the reference)
#define NN   10000   // nodes
#define EE   160000  // edges
#define WID  256     // node width
#define HIDD 512     // hidden
#define EWID 128     // edge embed width
#define TE   16      // edges per block in fused edge kernel
#define SP   516     // stage pitch (floats): 516%32=4 -> 2-way conflicts only

typedef __attribute__((ext_vector_type(8))) short bf16x8;
typedef __attribute__((ext_vector_type(4))) float f32x4;

__device__ __forceinline__ float geluf(float x) {
    return 0.5f * x * (1.0f + erff(x * 0.70710678118654752f));
}

// fp32 -> bf16 bits, round-to-nearest-even
__device__ __forceinline__ unsigned short f2bf(float f) {
    unsigned int u = __float_as_uint(f);
    u += 0x7fffu + ((u >> 16) & 1u);
    return (unsigned short)(u >> 16);
}

// ---------------- convert Wr0/1/2 [128x512 f32 row-major] -> WrT bf16 [p][n][k] ----------------
__global__ __launch_bounds__(256) void k_cvt(const float* __restrict__ W0,
                                             const float* __restrict__ W1,
                                             const float* __restrict__ W2,
                                             unsigned short* __restrict__ out) {
    int tid = blockIdx.x * 256 + threadIdx.x;       // 0..196607
    int p = tid >> 16;                               // matrix select (uniform per block)
    int rem = tid & 65535;
    int n = rem >> 7, k = rem & 127;
    const float* W = p == 0 ? W0 : p == 1 ? W1 : W2;
    out[tid] = f2bf(W[k * HIDD + n]);
}

// ---------------- pre: xx = LN(x @ W_pre + b_pre) ----------------
__global__ __launch_bounds__(256) void k_pre(const float* __restrict__ x,
                                             const float* __restrict__ Wp,
                                             const float* __restrict__ bp,
                                             float* __restrict__ xx) {
    __shared__ __align__(16) float xs[WID * 12];   // [i][g], pitch 12 (8 used)
    __shared__ __align__(16) float ot[8 * WID];
    __shared__ float mean_s[8], rstd_s[8];
    int t = threadIdx.x;
    int r0 = blockIdx.x * 8;
    #pragma unroll
    for (int g = 0; g < 8; ++g) {
        int r = r0 + g;
        xs[t * 12 + g] = (r < NN) ? x[r * WID + t] : 0.f;
    }
    __syncthreads();
    float acc[8];
    #pragma unroll
    for (int g = 0; g < 8; ++g) acc[g] = 0.f;
    for (int i = 0; i < WID; ++i) {
        float w = Wp[i * WID + t];
        float4 a0 = *(const float4*)&xs[i * 12];
        float4 a1 = *(const float4*)&xs[i * 12 + 4];
        acc[0] += a0.x * w; acc[1] += a0.y * w; acc[2] += a0.z * w; acc[3] += a0.w * w;
        acc[4] += a1.x * w; acc[5] += a1.y * w; acc[6] += a1.z * w; acc[7] += a1.w * w;
    }
    float bb = bp[t];
    #pragma unroll
    for (int g = 0; g < 8; ++g) ot[g * WID + t] = acc[g] + bb;
    __syncthreads();
    int wave = t >> 6, lane = t & 63;
    for (int r = wave * 2; r < wave * 2 + 2; ++r) {
        float s = 0.f, s2 = 0.f;
        #pragma unroll
        for (int k2 = 0; k2 < 4; ++k2) {
            float v = ot[r * WID + lane + 64 * k2];
            s += v; s2 += v * v;
        }
        #pragma unroll
        for (int off = 32; off >= 1; off >>= 1) {
            s  += __shfl_xor(s,  off, 64);
            s2 += __shfl_xor(s2, off, 64);
        }
        if (lane == 0) {
            float m = s * (1.f / WID);
            float var = s2 * (1.f / WID) - m * m;
            mean_s[r] = m;
            rstd_s[r] = rsqrtf(var + 1e-5f);
        }
    }
    __syncthreads();
    #pragma unroll
    for (int g = 0; g < 8; ++g) {
        int r = r0 + g;
        if (r < NN) xx[r * WID + t] = (ot[g * WID + t] - mean_s[g]) * rstd_s[g];
    }
}

// ---------------- node QKV + msg0: four 256x512 GEMMs off xx ----------------
// sel==3 (msg0) writes gelu(...) directly into agg, which k_edge then atomically
// accumulates into -- saves the M0 buffer and the k_zero pass.
__global__ __launch_bounds__(256) void k_qkvm(const float* __restrict__ xx,
    const float* __restrict__ Wq, const float* __restrict__ bq,
    const float* __restrict__ Wk, const float* __restrict__ bk,
    const float* __restrict__ Wv, const float* __restrict__ bv,
    const float* __restrict__ Wm, const float* __restrict__ bm,
    float* __restrict__ XQ, float* __restrict__ XK,
    float* __restrict__ XV, float* __restrict__ AG) {
    __shared__ __align__(16) float xs[WID * 20];   // [i][g], pitch 20 (16 used)
    int t = threadIdx.x;
    int r0 = blockIdx.x * 16;
    int chunk = blockIdx.y;          // 0..7
    int sel = chunk >> 1;
    int col = (chunk & 1) * 256 + t;
    const float* Wsel = sel == 0 ? Wq : sel == 1 ? Wk : sel == 2 ? Wv : Wm;
    const float* bsel = sel == 0 ? bq : sel == 1 ? bk : sel == 2 ? bv : bm;
    float* osel       = sel == 0 ? XQ : sel == 1 ? XK : sel == 2 ? XV : AG;
    #pragma unroll
    for (int g = 0; g < 16; ++g) {
        int r = r0 + g;
        xs[t * 20 + g] = (r < NN) ? xx[r * WID + t] : 0.f;
    }
    __syncthreads();
    float acc[16];
    #pragma unroll
    for (int g = 0; g < 16; ++g) acc[g] = 0.f;
    for (int i = 0; i < WID; ++i) {
        float w = Wsel[i * HIDD + col];
        #pragma unroll
        for (int q4 = 0; q4 < 4; ++q4) {
            float4 a = *(const float4*)&xs[i * 20 + q4 * 4];
            acc[q4 * 4 + 0] += a.x * w; acc[q4 * 4 + 1] += a.y * w;
            acc[q4 * 4 + 2] += a.z * w; acc[q4 * 4 + 3] += a.w * w;
        }
    }
    float bb = bsel[col];
    bool dogelu = (sel == 3);
    #pragma unroll
    for (int g = 0; g < 16; ++g) {
        int r = r0 + g;
        if (r < NN) {
            float v = acc[g] + bb;
            if (dogelu) v = geluf(v);
            osel[r * HIDD + col] = v;
        }
    }
}

// ---------------- fused edge kernel: bf16 MFMA R-GEMM + attention + scatter ----
// 16 edges/block. ee tile built directly in MFMA A-fragment order in LDS
// (chunk index == threadIdx -> conflict-free ds_read_b128). Per part, the
// [16x128]@[128x512] product runs on matrix cores (wave w owns cols
// 128w..128w+127: 8 col-tiles x 4 K-steps). D staged via padded LDS to recover
// the "thread t owns cols t,t+256" layout for attention/scatter.
__global__ __launch_bounds__(256) void k_edge(
    const int* __restrict__ eidx, const int* __restrict__ eattr,
    const float* __restrict__ eemb,
    const float* __restrict__ emb0, const float* __restrict__ emb1,
    const float* __restrict__ emb2, const float* __restrict__ emb3,
    const float* __restrict__ i0e, const float* __restrict__ i0,
    const float* __restrict__ XQ, const float* __restrict__ XK,
    const float* __restrict__ XV,
    const unsigned short* __restrict__ WrT,   // [3][512][128] bf16
    const float* __restrict__ br0, const float* __restrict__ br1,
    const float* __restrict__ br2,
    float* __restrict__ agg) {
    __shared__ __align__(16) unsigned short afrag[4 * 64 * 8];  // 4 KB, A-fragment order
    __shared__ __align__(16) float stage[TE * SP];              // 33 KB D staging
    __shared__ int dst_s[TE], src_s[TE];
    int t = threadIdx.x;
    int e0 = blockIdx.x * TE;
    if (t < TE) {
        src_s[t] = eidx[e0 + t];        // row 0 = j (source)
        dst_s[t] = eidx[EE + e0 + t];   // row 1 = i (target)
    }
    float ev0 = __expf(i0e[0]), ev1 = __expf(i0e[1]),
          ev2 = __expf(i0e[2]), ev3 = __expf(i0e[3]);
    float rs = rsqrtf(ev0 + ev1 + ev2 + ev3);
    float xw0 = ev0 * rs, xw1 = ev1 * rs, xw2 = ev2 * rs, xw3 = ev3 * rs;
    float a_sc = i0[0], a_bi = i0[1];
    float s_e = expf(i0[2]), s_v = expf(i0[3]);
    float c_sc = 0.125f * a_sc;                 // fold 1/sqrt(64) into scale

    // ---- build ee tile in A-fragment order: chunk == t ----
    {
        int m  = t & 15;                 // edge within tile
        int kb = t >> 6, qd = (t >> 4) & 3;
        int c0 = kb * 32 + qd * 8;       // this thread's 8 k-columns
        int ed = e0 + m;
        int a0 = eattr[ed * 4 + 0], a1 = eattr[ed * 4 + 1];
        int a2 = eattr[ed * 4 + 2], a3 = eattr[ed * 4 + 3];
        const float* p0 = &emb0[a0 * EWID + c0];
        const float* p1 = &emb1[a1 * EWID + c0];
        const float* p2 = &emb2[a2 * EWID + c0];
        const float* p3 = &emb3[a3 * EWID + c0];
        const float* pe = &eemb[ed * EWID + c0];
        bf16x8 pack;
        #pragma unroll
        for (int j = 0; j < 8; ++j) {
            float v = xw0 * p0[j] + xw1 * p1[j] + xw2 * p2[j] + xw3 * p3[j];
            pack[j] = (short)f2bf(0.5f * (v + pe[j]));
        }
        *(bf16x8*)&afrag[t * 8] = pack;
    }
    __syncthreads();

    int lane = t & 63, w = t >> 6;
    int l15 = lane & 15, quad = lane >> 4;
    bf16x8 af[4];
    #pragma unroll
    for (int kb = 0; kb < 4; ++kb)
        af[kb] = *(const bf16x8*)&afrag[(kb * 64 + lane) * 8];

    float q0[TE], q1[TE], att0[TE], att1[TE];

    #pragma unroll 1
    for (int part = 0; part < 3; ++part) {
        // ---- MFMA GEMM into stage ----
        const unsigned short* Bp = WrT + part * (HIDD * EWID);
        #pragma unroll
        for (int tb = 0; tb < 8; ++tb) {
            int col0 = w * 128 + tb * 16;
            f32x4 acc = {0.f, 0.f, 0.f, 0.f};
            #pragma unroll
            for (int kb = 0; kb < 4; ++kb) {
                bf16x8 bfr = *(const bf16x8*)&Bp[(col0 + l15) * EWID + kb * 32 + quad * 8];
                acc = __builtin_amdgcn_mfma_f32_16x16x32_bf16(af[kb], bfr, acc, 0, 0, 0);
            }
            #pragma unroll
            for (int r = 0; r < 4; ++r)
                stage[(quad * 4 + r) * SP + col0 + l15] = acc[r];
        }
        __syncthreads();
        // ---- consume in "thread t owns cols t, t+256" layout ----
        if (part == 0) {
            float bb0 = br0[t] * s_e, bb1 = br0[256 + t] * s_e;
            #pragma unroll
            for (int e = 0; e < TE; ++e) {
                int n = dst_s[e];
                q0[e] = XQ[n * HIDD + t]       + s_e * stage[e * SP + t]       + bb0;
                q1[e] = XQ[n * HIDD + 256 + t] + s_e * stage[e * SP + 256 + t] + bb1;
            }
        } else if (part == 1) {
            float bb0 = br1[t] * s_e, bb1 = br1[256 + t] * s_e;
            #pragma unroll
            for (int e = 0; e < TE; ++e) {
                int n = src_s[e];
                float k0 = XK[n * HIDD + t]       + s_e * stage[e * SP + t]       + bb0;
                float k1 = XK[n * HIDD + 256 + t] + s_e * stage[e * SP + 256 + t] + bb1;
                float d0 = q0[e] * k0;
                float d1 = q1[e] * k1;
                #pragma unroll
                for (int off = 32; off >= 1; off >>= 1) {
                    d0 += __shfl_xor(d0, off, 64);
                    d1 += __shfl_xor(d1, off, 64);
                }
                att0[e] = expf(d0 * c_sc + a_bi);
                att1[e] = expf(d1 * c_sc + a_bi);
            }
        } else {
            float bb0 = br2[t] * s_v, bb1 = br2[256 + t] * s_v;
            #pragma unroll
            for (int e = 0; e < TE; ++e) {
                int ns = src_s[e], nd = dst_s[e];
                float v0 = geluf(XV[ns * HIDD + t]       + s_v * stage[e * SP + t]       + bb0);
                float v1 = geluf(XV[ns * HIDD + 256 + t] + s_v * stage[e * SP + 256 + t] + bb1);
                atomicAdd(&agg[nd * HIDD + t],       v0 * att0[e]);
                atomicAdd(&agg[nd * HIDD + 256 + t], v1 * att1[e]);
            }
        }
        if (part < 2) __syncthreads();   // protect stage before next GEMM overwrites
    }
}

// ---------------- post: out = x + agg @ W_post + b_post ----------------
// (agg already holds gelu(msg0) + scatter sum)
__global__ __launch_bounds__(256) void k_post(const float* __restrict__ x,
    const float* __restrict__ agg,
    const float* __restrict__ Wp, const float* __restrict__ bp,
    float* __restrict__ out) {
    __shared__ __align__(16) float xs[HIDD * 20];  // [i][g] pitch 20 (16 used)
    int t = threadIdx.x;
    int r0 = blockIdx.x * 16;
    #pragma unroll
    for (int g = 0; g < 16; ++g) {
        int r = r0 + g;
        for (int h = 0; h < 2; ++h) {
            int i = h * 256 + t;
            xs[i * 20 + g] = (r < NN) ? agg[r * HIDD + i] : 0.f;
        }
    }
    __syncthreads();
    float acc[16];
    #pragma unroll
    for (int g = 0; g < 16; ++g) acc[g] = 0.f;
    for (int i = 0; i < HIDD; ++i) {
        float w = Wp[i * WID + t];
        #pragma unroll
        for (int q4 = 0; q4 < 4; ++q4) {
            float4 a = *(const float4*)&xs[i * 20 + q4 * 4];
            acc[q4 * 4 + 0] += a.x * w; acc[q4 * 4 + 1] += a.y * w;
            acc[q4 * 4 + 2] += a.z * w; acc[q4 * 4 + 3] += a.w * w;
        }
    }
    float bb = bp[t];
    #pragma unroll
    for (int g = 0; g < 16; ++g) {
        int r = r0 + g;
        if (r < NN) out[r * WID + t] = x[r * WID + t] + acc[g] + bb;
    }
}

extern "C" void kernel_launch(void* const* d_in, const int* in_sizes, int n_in,
                              void* d_out, int out_size, void* d_ws, size_t ws_size,
                              hipStream_t stream) {
    const float* x     = (const float*)d_in[0];
    const int*   eidx  = (const int*)  d_in[1];
    const int*   eattr = (const int*)  d_in[2];
    const float* eemb  = (const float*)d_in[3];
    const float* emb0  = (const float*)d_in[4];
    const float* emb1  = (const float*)d_in[5];
    const float* emb2  = (const float*)d_in[6];
    const float* emb3  = (const float*)d_in[7];
    const float* i0e   = (const float*)d_in[8];
    const float* i0    = (const float*)d_in[9];
    const float* Wpre  = (const float*)d_in[10];
    const float* bpre  = (const float*)d_in[11];
    const float* Wm    = (const float*)d_in[12];
    const float* bm    = (const float*)d_in[13];
    const float* Wq    = (const float*)d_in[14];
    const float* bq    = (const float*)d_in[15];
    const float* Wk    = (const float*)d_in[16];
    const float* bk    = (const float*)d_in[17];
    const float* Wv    = (const float*)d_in[18];
    const float* bv    = (const float*)d_in[19];
    const float* Wr0   = (const float*)d_in[20];
    const float* br0   = (const float*)d_in[21];
    const float* Wr1   = (const float*)d_in[22];
    const float* br1   = (const float*)d_in[23];
    const float* Wr2   = (const float*)d_in[24];
    const float* br2   = (const float*)d_in[25];
    const float* Wpost = (const float*)d_in[26];
    const float* bpost = (const float*)d_in[27];

    float* ws  = (float*)d_ws;
    float* xx  = ws;                         // N*256   = 2,560,000
    float* XQ  = ws + 2560000;               // N*512   = 5,120,000
    float* XK  = ws + 7680000;
    float* XV  = ws + 12800000;
    float* agg = ws + 17920000;              // N*512 -> ends 23,040,000
    unsigned short* WrT = (unsigned short*)(ws + 23040000);  // 3*512*128 bf16
    // total ~92.6 MB

    k_cvt<<<768, 256, 0, stream>>>(Wr0, Wr1, Wr2, WrT);
    k_pre<<<NN / 8, 256, 0, stream>>>(x, Wpre, bpre, xx);
    k_qkvm<<<dim3(NN / 16, 8), 256, 0, stream>>>(xx, Wq, bq, Wk, bk, Wv, bv, Wm, bm,
                                                 XQ, XK, XV, agg);
    k_edge<<<EE / TE, 256, 0, stream>>>(eidx, eattr, eemb, emb0, emb1, emb2, emb3,
                                        i0e, i0, XQ, XK, XV,
                                        WrT, br0, br1, br2, agg);
    k_post<<<NN / 16, 256, 0, stream>>>(x, agg, Wpost, bpost, (float*)d_out);
}

// Round 4
// 1067.296 us; speedup vs baseline: 2.9394x; 1.3228x over previous
//
#include <hip/hip_runtime.h>
#include <hip/hip_bf16.h>
#include <math.h>

// Problem constants (fixed by the reference)
#define NN   10000   // nodes
#define EE   160000  // edges
#define WID  256     // node width
#define HIDD 512     // hidden
#define EWID 128     // edge embed width
#define TE   16      // edges per block in fused edge kernel

typedef __attribute__((ext_vector_type(8))) short bf16x8;
typedef __attribute__((ext_vector_type(4))) float f32x4;

__device__ __forceinline__ float geluf(float x) {
    return 0.5f * x * (1.0f + erff(x * 0.70710678118654752f));
}

// fp32 -> bf16 bits, round-to-nearest-even
__device__ __forceinline__ unsigned short f2bf(float f) {
    unsigned int u = __float_as_uint(f);
    u += 0x7fffu + ((u >> 16) & 1u);
    return (unsigned short)(u >> 16);
}

// ---------------- convert Wr0/1/2 [128x512 f32 row-major] -> WrT bf16 [p][n][k] ----------------
__global__ __launch_bounds__(256) void k_cvt(const float* __restrict__ W0,
                                             const float* __restrict__ W1,
                                             const float* __restrict__ W2,
                                             unsigned short* __restrict__ out) {
    int tid = blockIdx.x * 256 + threadIdx.x;       // 0..196607
    int p = tid >> 16;                               // matrix select (uniform per block)
    int rem = tid & 65535;
    int n = rem >> 7, k = rem & 127;
    const float* W = p == 0 ? W0 : p == 1 ? W1 : W2;
    out[tid] = f2bf(W[k * HIDD + n]);
}

// ---------------- pre: xx = LN(x @ W_pre + b_pre) ----------------
__global__ __launch_bounds__(256) void k_pre(const float* __restrict__ x,
                                             const float* __restrict__ Wp,
                                             const float* __restrict__ bp,
                                             float* __restrict__ xx) {
    __shared__ __align__(16) float xs[WID * 12];   // [i][g], pitch 12 (8 used)
    __shared__ __align__(16) float ot[8 * WID];
    __shared__ float mean_s[8], rstd_s[8];
    int t = threadIdx.x;
    int r0 = blockIdx.x * 8;
    #pragma unroll
    for (int g = 0; g < 8; ++g) {
        int r = r0 + g;
        xs[t * 12 + g] = (r < NN) ? x[r * WID + t] : 0.f;
    }
    __syncthreads();
    float acc[8];
    #pragma unroll
    for (int g = 0; g < 8; ++g) acc[g] = 0.f;
    for (int i = 0; i < WID; ++i) {
        float w = Wp[i * WID + t];
        float4 a0 = *(const float4*)&xs[i * 12];
        float4 a1 = *(const float4*)&xs[i * 12 + 4];
        acc[0] += a0.x * w; acc[1] += a0.y * w; acc[2] += a0.z * w; acc[3] += a0.w * w;
        acc[4] += a1.x * w; acc[5] += a1.y * w; acc[6] += a1.z * w; acc[7] += a1.w * w;
    }
    float bb = bp[t];
    #pragma unroll
    for (int g = 0; g < 8; ++g) ot[g * WID + t] = acc[g] + bb;
    __syncthreads();
    int wave = t >> 6, lane = t & 63;
    for (int r = wave * 2; r < wave * 2 + 2; ++r) {
        float s = 0.f, s2 = 0.f;
        #pragma unroll
        for (int k2 = 0; k2 < 4; ++k2) {
            float v = ot[r * WID + lane + 64 * k2];
            s += v; s2 += v * v;
        }
        #pragma unroll
        for (int off = 32; off >= 1; off >>= 1) {
            s  += __shfl_xor(s,  off, 64);
            s2 += __shfl_xor(s2, off, 64);
        }
        if (lane == 0) {
            float m = s * (1.f / WID);
            float var = s2 * (1.f / WID) - m * m;
            mean_s[r] = m;
            rstd_s[r] = rsqrtf(var + 1e-5f);
        }
    }
    __syncthreads();
    #pragma unroll
    for (int g = 0; g < 8; ++g) {
        int r = r0 + g;
        if (r < NN) xx[r * WID + t] = (ot[g * WID + t] - mean_s[g]) * rstd_s[g];
    }
}

// ---------------- node QKV + msg0: four 256x512 GEMMs off xx ----------------
// sel==3 (msg0) writes gelu(...) directly into agg, which k_edge then atomically
// accumulates into -- saves the M0 buffer and the k_zero pass.
__global__ __launch_bounds__(256) void k_qkvm(const float* __restrict__ xx,
    const float* __restrict__ Wq, const float* __restrict__ bq,
    const float* __restrict__ Wk, const float* __restrict__ bk,
    const float* __restrict__ Wv, const float* __restrict__ bv,
    const float* __restrict__ Wm, const float* __restrict__ bm,
    float* __restrict__ XQ, float* __restrict__ XK,
    float* __restrict__ XV, float* __restrict__ AG) {
    __shared__ __align__(16) float xs[WID * 20];   // [i][g], pitch 20 (16 used)
    int t = threadIdx.x;
    int r0 = blockIdx.x * 16;
    int chunk = blockIdx.y;          // 0..7
    int sel = chunk >> 1;
    int col = (chunk & 1) * 256 + t;
    const float* Wsel = sel == 0 ? Wq : sel == 1 ? Wk : sel == 2 ? Wv : Wm;
    const float* bsel = sel == 0 ? bq : sel == 1 ? bk : sel == 2 ? bv : bm;
    float* osel       = sel == 0 ? XQ : sel == 1 ? XK : sel == 2 ? XV : AG;
    #pragma unroll
    for (int g = 0; g < 16; ++g) {
        int r = r0 + g;
        xs[t * 20 + g] = (r < NN) ? xx[r * WID + t] : 0.f;
    }
    __syncthreads();
    float acc[16];
    #pragma unroll
    for (int g = 0; g < 16; ++g) acc[g] = 0.f;
    for (int i = 0; i < WID; ++i) {
        float w = Wsel[i * HIDD + col];
        #pragma unroll
        for (int q4 = 0; q4 < 4; ++q4) {
            float4 a = *(const float4*)&xs[i * 20 + q4 * 4];
            acc[q4 * 4 + 0] += a.x * w; acc[q4 * 4 + 1] += a.y * w;
            acc[q4 * 4 + 2] += a.z * w; acc[q4 * 4 + 3] += a.w * w;
        }
    }
    float bb = bsel[col];
    bool dogelu = (sel == 3);
    #pragma unroll
    for (int g = 0; g < 16; ++g) {
        int r = r0 + g;
        if (r < NN) {
            float v = acc[g] + bb;
            if (dogelu) v = geluf(v);
            osel[r * HIDD + col] = v;
        }
    }
}

// ---------------- fused edge kernel: MFMA R-GEMM, D consumed in registers ----
// 16 edges/block. MFMA D layout: lane(quad,l15) holds edge=quad*4+r,
// col=w*128+tb*16+l15. Attention head h = col>>6 lives entirely within the
// 16-lane l15 group -> 4-level butterfly gives per-edge per-head dots.
// Node terms (XQ/XK/XV) gathered directly in D layout (64B segments).
// Biases folded into MFMA accumulator init. Single __syncthreads; no stage.
__global__ __launch_bounds__(256, 4) void k_edge(
    const int* __restrict__ eidx, const int* __restrict__ eattr,
    const float* __restrict__ eemb,
    const float* __restrict__ emb0, const float* __restrict__ emb1,
    const float* __restrict__ emb2, const float* __restrict__ emb3,
    const float* __restrict__ i0e, const float* __restrict__ i0,
    const float* __restrict__ XQ, const float* __restrict__ XK,
    const float* __restrict__ XV,
    const unsigned short* __restrict__ WrT,   // [3][512][128] bf16
    const float* __restrict__ br0, const float* __restrict__ br1,
    const float* __restrict__ br2,
    float* __restrict__ agg) {
    __shared__ __align__(16) unsigned short afrag[4 * 64 * 8];  // 4 KB A-fragments
    __shared__ float brs[3 * HIDD];                             // 6 KB biases
    __shared__ int dst_s[TE], src_s[TE];
    int t = threadIdx.x;
    int e0 = blockIdx.x * TE;
    if (t < TE) {
        src_s[t] = eidx[e0 + t];        // row 0 = j (source)
        dst_s[t] = eidx[EE + e0 + t];   // row 1 = i (target)
    }
    // biases (raw; scales applied at consume time)
    brs[t]        = br0[t];  brs[256 + t]  = br0[256 + t];
    brs[512 + t]  = br1[t];  brs[768 + t]  = br1[256 + t];
    brs[1024 + t] = br2[t];  brs[1280 + t] = br2[256 + t];

    float ev0 = __expf(i0e[0]), ev1 = __expf(i0e[1]),
          ev2 = __expf(i0e[2]), ev3 = __expf(i0e[3]);
    float rs = rsqrtf(ev0 + ev1 + ev2 + ev3);
    float xw0 = ev0 * rs, xw1 = ev1 * rs, xw2 = ev2 * rs, xw3 = ev3 * rs;
    float a_sc = i0[0], a_bi = i0[1];
    float s_e = expf(i0[2]), s_v = expf(i0[3]);
    float c_sc = 0.125f * a_sc;                 // fold 1/sqrt(64) into scale

    // ---- build ee tile in A-fragment order: chunk == t ----
    {
        int m  = t & 15;                 // edge within tile
        int kb = t >> 6, qd = (t >> 4) & 3;
        int c0 = kb * 32 + qd * 8;       // this thread's 8 k-columns
        int ed = e0 + m;
        int a0 = eattr[ed * 4 + 0], a1 = eattr[ed * 4 + 1];
        int a2 = eattr[ed * 4 + 2], a3 = eattr[ed * 4 + 3];
        const float* p0 = &emb0[a0 * EWID + c0];
        const float* p1 = &emb1[a1 * EWID + c0];
        const float* p2 = &emb2[a2 * EWID + c0];
        const float* p3 = &emb3[a3 * EWID + c0];
        const float* pe = &eemb[ed * EWID + c0];
        bf16x8 pack;
        #pragma unroll
        for (int j = 0; j < 8; ++j) {
            float v = xw0 * p0[j] + xw1 * p1[j] + xw2 * p2[j] + xw3 * p3[j];
            pack[j] = (short)f2bf(0.5f * (v + pe[j]));
        }
        *(bf16x8*)&afrag[t * 8] = pack;
    }
    __syncthreads();

    int lane = t & 63, w = t >> 6;
    int l15 = lane & 15, quad = lane >> 4;
    bf16x8 af[4];
    #pragma unroll
    for (int kb = 0; kb < 4; ++kb)
        af[kb] = *(const bf16x8*)&afrag[(kb * 64 + lane) * 8];

    // per-lane gather bases: edges quad*4+r
    int nd[4], ns[4];
    #pragma unroll
    for (int r = 0; r < 4; ++r) {
        nd[r] = dst_s[quad * 4 + r] * HIDD + l15;
        ns[r] = src_s[quad * 4 + r] * HIDD + l15;
    }

    // ---- part 0: Q ----
    float q[8][4];
    #pragma unroll
    for (int tb = 0; tb < 8; ++tb) {
        int c = w * 128 + tb * 16;
        float bias = brs[c + l15];
        f32x4 acc = {bias, bias, bias, bias};
        #pragma unroll
        for (int kb = 0; kb < 4; ++kb) {
            bf16x8 bfr = *(const bf16x8*)&WrT[(c + l15) * EWID + kb * 32 + quad * 8];
            acc = __builtin_amdgcn_mfma_f32_16x16x32_bf16(af[kb], bfr, acc, 0, 0, 0);
        }
        #pragma unroll
        for (int r = 0; r < 4; ++r)
            q[tb][r] = XQ[nd[r] + c] + s_e * acc[r];
    }
    // ---- part 1: K + attention dots ----
    float d0[4] = {0.f, 0.f, 0.f, 0.f}, d1[4] = {0.f, 0.f, 0.f, 0.f};
    #pragma unroll
    for (int tb = 0; tb < 8; ++tb) {
        int c = w * 128 + tb * 16;
        float bias = brs[HIDD + c + l15];
        f32x4 acc = {bias, bias, bias, bias};
        #pragma unroll
        for (int kb = 0; kb < 4; ++kb) {
            bf16x8 bfr = *(const bf16x8*)&WrT[(HIDD * EWID) + (c + l15) * EWID + kb * 32 + quad * 8];
            acc = __builtin_amdgcn_mfma_f32_16x16x32_bf16(af[kb], bfr, acc, 0, 0, 0);
        }
        #pragma unroll
        for (int r = 0; r < 4; ++r) {
            float kv = XK[ns[r] + c] + s_e * acc[r];
            float p = q[tb][r] * kv;
            if (tb < 4) d0[r] += p; else d1[r] += p;
        }
    }
    float att0[4], att1[4];
    #pragma unroll
    for (int off = 8; off >= 1; off >>= 1) {
        #pragma unroll
        for (int r = 0; r < 4; ++r) {
            d0[r] += __shfl_xor(d0[r], off, 64);
            d1[r] += __shfl_xor(d1[r], off, 64);
        }
    }
    #pragma unroll
    for (int r = 0; r < 4; ++r) {
        att0[r] = expf(d0[r] * c_sc + a_bi);
        att1[r] = expf(d1[r] * c_sc + a_bi);
    }
    // ---- part 2: V + scatter ----
    #pragma unroll
    for (int tb = 0; tb < 8; ++tb) {
        int c = w * 128 + tb * 16;
        float bias = brs[2 * HIDD + c + l15];
        f32x4 acc = {bias, bias, bias, bias};
        #pragma unroll
        for (int kb = 0; kb < 4; ++kb) {
            bf16x8 bfr = *(const bf16x8*)&WrT[2 * (HIDD * EWID) + (c + l15) * EWID + kb * 32 + quad * 8];
            acc = __builtin_amdgcn_mfma_f32_16x16x32_bf16(af[kb], bfr, acc, 0, 0, 0);
        }
        #pragma unroll
        for (int r = 0; r < 4; ++r) {
            float v = geluf(XV[ns[r] + c] + s_v * acc[r]);
            float m = v * (tb < 4 ? att0[r] : att1[r]);
            atomicAdd(&agg[nd[r] + c], m);
        }
    }
}

// ---------------- post: out = x + agg @ W_post + b_post ----------------
// (agg already holds gelu(msg0) + scatter sum)
__global__ __launch_bounds__(256) void k_post(const float* __restrict__ x,
    const float* __restrict__ agg,
    const float* __restrict__ Wp, const float* __restrict__ bp,
    float* __restrict__ out) {
    __shared__ __align__(16) float xs[HIDD * 20];  // [i][g] pitch 20 (16 used)
    int t = threadIdx.x;
    int r0 = blockIdx.x * 16;
    #pragma unroll
    for (int g = 0; g < 16; ++g) {
        int r = r0 + g;
        for (int h = 0; h < 2; ++h) {
            int i = h * 256 + t;
            xs[i * 20 + g] = (r < NN) ? agg[r * HIDD + i] : 0.f;
        }
    }
    __syncthreads();
    float acc[16];
    #pragma unroll
    for (int g = 0; g < 16; ++g) acc[g] = 0.f;
    for (int i = 0; i < HIDD; ++i) {
        float w = Wp[i * WID + t];
        #pragma unroll
        for (int q4 = 0; q4 < 4; ++q4) {
            float4 a = *(const float4*)&xs[i * 20 + q4 * 4];
            acc[q4 * 4 + 0] += a.x * w; acc[q4 * 4 + 1] += a.y * w;
            acc[q4 * 4 + 2] += a.z * w; acc[q4 * 4 + 3] += a.w * w;
        }
    }
    float bb = bp[t];
    #pragma unroll
    for (int g = 0; g < 16; ++g) {
        int r = r0 + g;
        if (r < NN) out[r * WID + t] = x[r * WID + t] + acc[g] + bb;
    }
}

extern "C" void kernel_launch(void* const* d_in, const int* in_sizes, int n_in,
                              void* d_out, int out_size, void* d_ws, size_t ws_size,
                              hipStream_t stream) {
    const float* x     = (const float*)d_in[0];
    const int*   eidx  = (const int*)  d_in[1];
    const int*   eattr = (const int*)  d_in[2];
    const float* eemb  = (const float*)d_in[3];
    const float* emb0  = (const float*)d_in[4];
    const float* emb1  = (const float*)d_in[5];
    const float* emb2  = (const float*)d_in[6];
    const float* emb3  = (const float*)d_in[7];
    const float* i0e   = (const float*)d_in[8];
    const float* i0    = (const float*)d_in[9];
    const float* Wpre  = (const float*)d_in[10];
    const float* bpre  = (const float*)d_in[11];
    const float* Wm    = (const float*)d_in[12];
    const float* bm    = (const float*)d_in[13];
    const float* Wq    = (const float*)d_in[14];
    const float* bq    = (const float*)d_in[15];
    const float* Wk    = (const float*)d_in[16];
    const float* bk    = (const float*)d_in[17];
    const float* Wv    = (const float*)d_in[18];
    const float* bv    = (const float*)d_in[19];
    const float* Wr0   = (const float*)d_in[20];
    const float* br0   = (const float*)d_in[21];
    const float* Wr1   = (const float*)d_in[22];
    const float* br1   = (const float*)d_in[23];
    const float* Wr2   = (const float*)d_in[24];
    const float* br2   = (const float*)d_in[25];
    const float* Wpost = (const float*)d_in[26];
    const float* bpost = (const float*)d_in[27];

    float* ws  = (float*)d_ws;
    float* xx  = ws;                         // N*256   = 2,560,000
    float* XQ  = ws + 2560000;               // N*512   = 5,120,000
    float* XK  = ws + 7680000;
    float* XV  = ws + 12800000;
    float* agg = ws + 17920000;              // N*512 -> ends 23,040,000
    unsigned short* WrT = (unsigned short*)(ws + 23040000);  // 3*512*128 bf16
    // total ~92.6 MB

    k_cvt<<<768, 256, 0, stream>>>(Wr0, Wr1, Wr2, WrT);
    k_pre<<<NN / 8, 256, 0, stream>>>(x, Wpre, bpre, xx);
    k_qkvm<<<dim3(NN / 16, 8), 256, 0, stream>>>(xx, Wq, bq, Wk, bk, Wv, bv, Wm, bm,
                                                 XQ, XK, XV, agg);
    k_edge<<<EE / TE, 256, 0, stream>>>(eidx, eattr, eemb, emb0, emb1, emb2, emb3,
                                        i0e, i0, XQ, XK, XV,
                                        WrT, br0, br1, br2, agg);
    k_post<<<NN / 16, 256, 0, stream>>>(x, agg, Wpost, bpost, (float*)d_out);
}

// Round 5
// 932.494 us; speedup vs baseline: 3.3644x; 1.1446x over previous
//
#include <hip/hip_runtime.h>
#include <hip/hip_bf16.h>
#include <math.h>

// Problem constants (fixed by the reference)
#define NN   10000   // nodes
#define EE   160000  // edges
#define WID  256     // node width
#define HIDD 512     // hidden
#define EWID 128     // edge embed width
#define TE   16      // edges per block in fused edge kernel

typedef __attribute__((ext_vector_type(8))) short bf16x8;
typedef __attribute__((ext_vector_type(4))) float f32x4;

__device__ __forceinline__ float geluf(float x) {
    return 0.5f * x * (1.0f + erff(x * 0.70710678118654752f));
}

// fp32 -> bf16 bits, round-to-nearest-even
__device__ __forceinline__ unsigned short f2bf(float f) {
    unsigned int u = __float_as_uint(f);
    u += 0x7fffu + ((u >> 16) & 1u);
    return (unsigned short)(u >> 16);
}

// ---------------- convert Wr0/1/2 [128x512 f32] -> WrT bf16 [p][n=512][k=128] ----------------
__global__ __launch_bounds__(256) void k_cvt(const float* __restrict__ W0,
                                             const float* __restrict__ W1,
                                             const float* __restrict__ W2,
                                             unsigned short* __restrict__ out) {
    int tid = blockIdx.x * 256 + threadIdx.x;       // 0..196607
    int p = tid >> 16;
    int rem = tid & 65535;
    int n = rem >> 7, k = rem & 127;
    const float* W = p == 0 ? W0 : p == 1 ? W1 : W2;
    out[tid] = f2bf(W[k * HIDD + n]);
}

// ------------- convert Wq/Wk/Wv/Wm [256x512 f32] -> WTn bf16 [sel][n=512][k=256] -------------
__global__ __launch_bounds__(256) void k_cvtn(const float* __restrict__ W0,
                                              const float* __restrict__ W1,
                                              const float* __restrict__ W2,
                                              const float* __restrict__ W3,
                                              unsigned short* __restrict__ out) {
    int tid = blockIdx.x * 256 + threadIdx.x;       // 0..524287
    int sel = tid >> 17;
    int rem = tid & 131071;
    int n = rem >> 8, k = rem & 255;
    const float* W = sel == 0 ? W0 : sel == 1 ? W1 : sel == 2 ? W2 : W3;
    out[tid] = f2bf(W[k * HIDD + n]);
}

// ---------------- pre: xxb = bf16(LN(x @ W_pre + b_pre)) ----------------
__global__ __launch_bounds__(256) void k_pre(const float* __restrict__ x,
                                             const float* __restrict__ Wp,
                                             const float* __restrict__ bp,
                                             unsigned short* __restrict__ xxb) {
    __shared__ __align__(16) float xs[WID * 12];   // [i][g], pitch 12 (8 used)
    __shared__ __align__(16) float ot[8 * WID];
    __shared__ float mean_s[8], rstd_s[8];
    int t = threadIdx.x;
    int r0 = blockIdx.x * 8;
    #pragma unroll
    for (int g = 0; g < 8; ++g) {
        int r = r0 + g;
        xs[t * 12 + g] = (r < NN) ? x[r * WID + t] : 0.f;
    }
    __syncthreads();
    float acc[8];
    #pragma unroll
    for (int g = 0; g < 8; ++g) acc[g] = 0.f;
    for (int i = 0; i < WID; ++i) {
        float w = Wp[i * WID + t];
        float4 a0 = *(const float4*)&xs[i * 12];
        float4 a1 = *(const float4*)&xs[i * 12 + 4];
        acc[0] += a0.x * w; acc[1] += a0.y * w; acc[2] += a0.z * w; acc[3] += a0.w * w;
        acc[4] += a1.x * w; acc[5] += a1.y * w; acc[6] += a1.z * w; acc[7] += a1.w * w;
    }
    float bb = bp[t];
    #pragma unroll
    for (int g = 0; g < 8; ++g) ot[g * WID + t] = acc[g] + bb;
    __syncthreads();
    int wave = t >> 6, lane = t & 63;
    for (int r = wave * 2; r < wave * 2 + 2; ++r) {
        float s = 0.f, s2 = 0.f;
        #pragma unroll
        for (int k2 = 0; k2 < 4; ++k2) {
            float v = ot[r * WID + lane + 64 * k2];
            s += v; s2 += v * v;
        }
        #pragma unroll
        for (int off = 32; off >= 1; off >>= 1) {
            s  += __shfl_xor(s,  off, 64);
            s2 += __shfl_xor(s2, off, 64);
        }
        if (lane == 0) {
            float m = s * (1.f / WID);
            float var = s2 * (1.f / WID) - m * m;
            mean_s[r] = m;
            rstd_s[r] = rsqrtf(var + 1e-5f);
        }
    }
    __syncthreads();
    #pragma unroll
    for (int g = 0; g < 8; ++g) {
        int r = r0 + g;
        if (r < NN) xxb[r * WID + t] = f2bf((ot[g * WID + t] - mean_s[g]) * rstd_s[g]);
    }
}

// ---------------- node QKV + msg0 via MFMA ----------------
// grid (625, 4): 16 rows/block, sel = Q/K/V/M. No LDS: per-lane direct A/B
// fragment loads. sel<3 writes pair-packed bf16: dword idx = node*256 +
// w*64 + (tb>>1)*16 + l15; lo-ushort = col w*128+(tb>>1)*32+l15 (tb even),
// hi-ushort = +16 (tb odd). sel==3 writes gelu() f32 into agg.
__global__ __launch_bounds__(256, 4) void k_qkvm(
    const unsigned short* __restrict__ xxb,   // [N][256] bf16
    const unsigned short* __restrict__ WTn,   // [4][512][256] bf16
    const float* __restrict__ bq, const float* __restrict__ bk,
    const float* __restrict__ bv, const float* __restrict__ bm,
    unsigned short* __restrict__ XQp, unsigned short* __restrict__ XKp,
    unsigned short* __restrict__ XVp, float* __restrict__ AG) {
    int t = threadIdx.x;
    int r0 = blockIdx.x * 16;
    int sel = blockIdx.y;
    const float* bsel = sel == 0 ? bq : sel == 1 ? bk : sel == 2 ? bv : bm;
    const unsigned short* Wp = WTn + sel * (HIDD * WID);
    unsigned short* outp = sel == 0 ? XQp : sel == 1 ? XKp : XVp;
    int lane = t & 63, w = t >> 6;
    int l15 = lane & 15, quad = lane >> 4;
    bf16x8 af[8];
    #pragma unroll
    for (int kb = 0; kb < 8; ++kb)
        af[kb] = *(const bf16x8*)&xxb[(r0 + l15) * WID + kb * 32 + quad * 8];
    #pragma unroll
    for (int tb = 0; tb < 8; ++tb) {
        int c = w * 128 + tb * 16;
        float bias = bsel[c + l15];
        f32x4 acc = {bias, bias, bias, bias};
        #pragma unroll
        for (int kb = 0; kb < 8; ++kb) {
            bf16x8 bfr = *(const bf16x8*)&Wp[(c + l15) * WID + kb * 32 + quad * 8];
            acc = __builtin_amdgcn_mfma_f32_16x16x32_bf16(af[kb], bfr, acc, 0, 0, 0);
        }
        if (sel < 3) {
            int base = ((w * 64 + (tb >> 1) * 16 + l15) << 1) + (tb & 1);
            #pragma unroll
            for (int r = 0; r < 4; ++r) {
                int node = r0 + quad * 4 + r;
                outp[node * 512 + base] = f2bf(acc[r]);
            }
        } else {
            #pragma unroll
            for (int r = 0; r < 4; ++r) {
                int node = r0 + quad * 4 + r;
                AG[node * HIDD + c + l15] = geluf(acc[r]);
            }
        }
    }
}

// ---------------- fused edge kernel: MFMA R-GEMM + packed bf16 node gathers ----
__global__ __launch_bounds__(256, 4) void k_edge(
    const int* __restrict__ eidx, const int* __restrict__ eattr,
    const float* __restrict__ eemb,
    const float* __restrict__ emb0, const float* __restrict__ emb1,
    const float* __restrict__ emb2, const float* __restrict__ emb3,
    const float* __restrict__ i0e, const float* __restrict__ i0,
    const unsigned int* __restrict__ XQp, const unsigned int* __restrict__ XKp,
    const unsigned int* __restrict__ XVp,
    const unsigned short* __restrict__ WrT,   // [3][512][128] bf16
    const float* __restrict__ br0, const float* __restrict__ br1,
    const float* __restrict__ br2,
    float* __restrict__ agg) {
    __shared__ __align__(16) unsigned short afrag[4 * 64 * 8];  // 4 KB A-fragments
    __shared__ float brs[3 * HIDD];                             // 6 KB biases
    __shared__ int dst_s[TE], src_s[TE];
    int t = threadIdx.x;
    int e0 = blockIdx.x * TE;
    if (t < TE) {
        src_s[t] = eidx[e0 + t];        // row 0 = j (source)
        dst_s[t] = eidx[EE + e0 + t];   // row 1 = i (target)
    }
    brs[t]        = br0[t];  brs[256 + t]  = br0[256 + t];
    brs[512 + t]  = br1[t];  brs[768 + t]  = br1[256 + t];
    brs[1024 + t] = br2[t];  brs[1280 + t] = br2[256 + t];

    float ev0 = __expf(i0e[0]), ev1 = __expf(i0e[1]),
          ev2 = __expf(i0e[2]), ev3 = __expf(i0e[3]);
    float rs = rsqrtf(ev0 + ev1 + ev2 + ev3);
    float xw0 = ev0 * rs, xw1 = ev1 * rs, xw2 = ev2 * rs, xw3 = ev3 * rs;
    float a_sc = i0[0], a_bi = i0[1];
    float s_e = expf(i0[2]), s_v = expf(i0[3]);
    float c_sc = 0.125f * a_sc;

    // ---- build ee tile in A-fragment order: chunk == t ----
    {
        int m  = t & 15;
        int kb = t >> 6, qd = (t >> 4) & 3;
        int c0 = kb * 32 + qd * 8;
        int ed = e0 + m;
        int a0 = eattr[ed * 4 + 0], a1 = eattr[ed * 4 + 1];
        int a2 = eattr[ed * 4 + 2], a3 = eattr[ed * 4 + 3];
        const float* p0 = &emb0[a0 * EWID + c0];
        const float* p1 = &emb1[a1 * EWID + c0];
        const float* p2 = &emb2[a2 * EWID + c0];
        const float* p3 = &emb3[a3 * EWID + c0];
        const float* pe = &eemb[ed * EWID + c0];
        bf16x8 pack;
        #pragma unroll
        for (int j = 0; j < 8; ++j) {
            float v = xw0 * p0[j] + xw1 * p1[j] + xw2 * p2[j] + xw3 * p3[j];
            pack[j] = (short)f2bf(0.5f * (v + pe[j]));
        }
        *(bf16x8*)&afrag[t * 8] = pack;
    }
    __syncthreads();

    int lane = t & 63, w = t >> 6;
    int l15 = lane & 15, quad = lane >> 4;
    bf16x8 af[4];
    #pragma unroll
    for (int kb = 0; kb < 4; ++kb)
        af[kb] = *(const bf16x8*)&afrag[(kb * 64 + lane) * 8];

    // per-lane gather bases: edges quad*4+r
    int ndp[4], nsp[4], nda[4];
    #pragma unroll
    for (int r = 0; r < 4; ++r) {
        int dn = dst_s[quad * 4 + r], sn = src_s[quad * 4 + r];
        ndp[r] = dn * 256 + w * 64 + l15;      // packed-dword index
        nsp[r] = sn * 256 + w * 64 + l15;
        nda[r] = dn * HIDD + w * 128 + l15;    // f32 agg index
    }

    // ---- part 0: Q ----
    unsigned int pq[4][4];
    #pragma unroll
    for (int a = 0; a < 4; ++a)
        #pragma unroll
        for (int r = 0; r < 4; ++r) pq[a][r] = XQp[ndp[r] + a * 16];
    float q[8][4];
    #pragma unroll
    for (int tb = 0; tb < 8; ++tb) {
        int c = w * 128 + tb * 16;
        float bias = brs[c + l15];
        f32x4 acc = {bias, bias, bias, bias};
        #pragma unroll
        for (int kb = 0; kb < 4; ++kb) {
            bf16x8 bfr = *(const bf16x8*)&WrT[(c + l15) * EWID + kb * 32 + quad * 8];
            acc = __builtin_amdgcn_mfma_f32_16x16x32_bf16(af[kb], bfr, acc, 0, 0, 0);
        }
        #pragma unroll
        for (int r = 0; r < 4; ++r) {
            unsigned int u = pq[tb >> 1][r];
            float nodeterm = (tb & 1) ? __uint_as_float(u & 0xffff0000u)
                                      : __uint_as_float(u << 16);
            q[tb][r] = nodeterm + s_e * acc[r];
        }
    }
    // ---- part 1: K + attention dots ----
    unsigned int pk[4][4];
    #pragma unroll
    for (int a = 0; a < 4; ++a)
        #pragma unroll
        for (int r = 0; r < 4; ++r) pk[a][r] = XKp[nsp[r] + a * 16];
    float d0[4] = {0.f, 0.f, 0.f, 0.f}, d1[4] = {0.f, 0.f, 0.f, 0.f};
    #pragma unroll
    for (int tb = 0; tb < 8; ++tb) {
        int c = w * 128 + tb * 16;
        float bias = brs[HIDD + c + l15];
        f32x4 acc = {bias, bias, bias, bias};
        #pragma unroll
        for (int kb = 0; kb < 4; ++kb) {
            bf16x8 bfr = *(const bf16x8*)&WrT[(HIDD * EWID) + (c + l15) * EWID + kb * 32 + quad * 8];
            acc = __builtin_amdgcn_mfma_f32_16x16x32_bf16(af[kb], bfr, acc, 0, 0, 0);
        }
        #pragma unroll
        for (int r = 0; r < 4; ++r) {
            unsigned int u = pk[tb >> 1][r];
            float nodeterm = (tb & 1) ? __uint_as_float(u & 0xffff0000u)
                                      : __uint_as_float(u << 16);
            float kv = nodeterm + s_e * acc[r];
            float p = q[tb][r] * kv;
            if (tb < 4) d0[r] += p; else d1[r] += p;
        }
    }
    float att0[4], att1[4];
    #pragma unroll
    for (int off = 8; off >= 1; off >>= 1) {
        #pragma unroll
        for (int r = 0; r < 4; ++r) {
            d0[r] += __shfl_xor(d0[r], off, 64);
            d1[r] += __shfl_xor(d1[r], off, 64);
        }
    }
    #pragma unroll
    for (int r = 0; r < 4; ++r) {
        att0[r] = expf(d0[r] * c_sc + a_bi);
        att1[r] = expf(d1[r] * c_sc + a_bi);
    }
    // ---- part 2: V + scatter ----
    unsigned int pv[4][4];
    #pragma unroll
    for (int a = 0; a < 4; ++a)
        #pragma unroll
        for (int r = 0; r < 4; ++r) pv[a][r] = XVp[nsp[r] + a * 16];
    #pragma unroll
    for (int tb = 0; tb < 8; ++tb) {
        int c = w * 128 + tb * 16;
        float bias = brs[2 * HIDD + c + l15];
        f32x4 acc = {bias, bias, bias, bias};
        #pragma unroll
        for (int kb = 0; kb < 4; ++kb) {
            bf16x8 bfr = *(const bf16x8*)&WrT[2 * (HIDD * EWID) + (c + l15) * EWID + kb * 32 + quad * 8];
            acc = __builtin_amdgcn_mfma_f32_16x16x32_bf16(af[kb], bfr, acc, 0, 0, 0);
        }
        #pragma unroll
        for (int r = 0; r < 4; ++r) {
            unsigned int u = pv[tb >> 1][r];
            float nodeterm = (tb & 1) ? __uint_as_float(u & 0xffff0000u)
                                      : __uint_as_float(u << 16);
            float v = geluf(nodeterm + s_v * acc[r]);
            float m = v * (tb < 4 ? att0[r] : att1[r]);
            atomicAdd(&agg[nda[r] + tb * 16], m);
        }
    }
}

// ---------------- post: out = x + agg @ W_post + b_post ----------------
__global__ __launch_bounds__(256) void k_post(const float* __restrict__ x,
    const float* __restrict__ agg,
    const float* __restrict__ Wp, const float* __restrict__ bp,
    float* __restrict__ out) {
    __shared__ __align__(16) float xs[HIDD * 20];  // [i][g] pitch 20 (16 used)
    int t = threadIdx.x;
    int r0 = blockIdx.x * 16;
    #pragma unroll
    for (int g = 0; g < 16; ++g) {
        int r = r0 + g;
        for (int h = 0; h < 2; ++h) {
            int i = h * 256 + t;
            xs[i * 20 + g] = (r < NN) ? agg[r * HIDD + i] : 0.f;
        }
    }
    __syncthreads();
    float acc[16];
    #pragma unroll
    for (int g = 0; g < 16; ++g) acc[g] = 0.f;
    for (int i = 0; i < HIDD; ++i) {
        float w = Wp[i * WID + t];
        #pragma unroll
        for (int q4 = 0; q4 < 4; ++q4) {
            float4 a = *(const float4*)&xs[i * 20 + q4 * 4];
            acc[q4 * 4 + 0] += a.x * w; acc[q4 * 4 + 1] += a.y * w;
            acc[q4 * 4 + 2] += a.z * w; acc[q4 * 4 + 3] += a.w * w;
        }
    }
    float bb = bp[t];
    #pragma unroll
    for (int g = 0; g < 16; ++g) {
        int r = r0 + g;
        if (r < NN) out[r * WID + t] = x[r * WID + t] + acc[g] + bb;
    }
}

extern "C" void kernel_launch(void* const* d_in, const int* in_sizes, int n_in,
                              void* d_out, int out_size, void* d_ws, size_t ws_size,
                              hipStream_t stream) {
    const float* x     = (const float*)d_in[0];
    const int*   eidx  = (const int*)  d_in[1];
    const int*   eattr = (const int*)  d_in[2];
    const float* eemb  = (const float*)d_in[3];
    const float* emb0  = (const float*)d_in[4];
    const float* emb1  = (const float*)d_in[5];
    const float* emb2  = (const float*)d_in[6];
    const float* emb3  = (const float*)d_in[7];
    const float* i0e   = (const float*)d_in[8];
    const float* i0    = (const float*)d_in[9];
    const float* Wpre  = (const float*)d_in[10];
    const float* bpre  = (const float*)d_in[11];
    const float* Wm    = (const float*)d_in[12];
    const float* bm    = (const float*)d_in[13];
    const float* Wq    = (const float*)d_in[14];
    const float* bq    = (const float*)d_in[15];
    const float* Wk    = (const float*)d_in[16];
    const float* bk    = (const float*)d_in[17];
    const float* Wv    = (const float*)d_in[18];
    const float* bv    = (const float*)d_in[19];
    const float* Wr0   = (const float*)d_in[20];
    const float* br0   = (const float*)d_in[21];
    const float* Wr1   = (const float*)d_in[22];
    const float* br1   = (const float*)d_in[23];
    const float* Wr2   = (const float*)d_in[24];
    const float* br2   = (const float*)d_in[25];
    const float* Wpost = (const float*)d_in[26];
    const float* bpost = (const float*)d_in[27];

    float* ws  = (float*)d_ws;
    float* agg = ws;                                          // N*512 f32
    unsigned short* xxb = (unsigned short*)(ws + 5120000);    // N*256 bf16
    unsigned short* XQp = (unsigned short*)(ws + 6400000);    // N*512 bf16 packed
    unsigned short* XKp = (unsigned short*)(ws + 8960000);
    unsigned short* XVp = (unsigned short*)(ws + 11520000);
    unsigned short* WrT = (unsigned short*)(ws + 14080000);   // 3*512*128 bf16
    unsigned short* WTn = (unsigned short*)(ws + 14178304);   // 4*512*256 bf16
    // total ~57.8 MB

    k_cvt<<<768, 256, 0, stream>>>(Wr0, Wr1, Wr2, WrT);
    k_cvtn<<<2048, 256, 0, stream>>>(Wq, Wk, Wv, Wm, WTn);
    k_pre<<<NN / 8, 256, 0, stream>>>(x, Wpre, bpre, xxb);
    k_qkvm<<<dim3(625, 4), 256, 0, stream>>>(xxb, WTn, bq, bk, bv, bm,
                                             XQp, XKp, XVp, agg);
    k_edge<<<EE / TE, 256, 0, stream>>>(eidx, eattr, eemb, emb0, emb1, emb2, emb3,
                                        i0e, i0,
                                        (const unsigned int*)XQp,
                                        (const unsigned int*)XKp,
                                        (const unsigned int*)XVp,
                                        WrT, br0, br1, br2, agg);
    k_post<<<NN / 16, 256, 0, stream>>>(x, agg, Wpost, bpost, (float*)d_out);
}

// Round 6
// 758.489 us; speedup vs baseline: 4.1362x; 1.2294x over previous
//
#include <hip/hip_runtime.h>
#include <hip/hip_bf16.h>
#include <math.h>

// Problem constants (fixed by the reference)
#define NN   10000   // nodes
#define EE   160000  // edges
#define WID  256     // node width
#define HIDD 512     // hidden
#define EWID 128     // edge embed width

typedef __attribute__((ext_vector_type(8))) short bf16x8;
typedef __attribute__((ext_vector_type(4))) float f32x4;

__device__ __forceinline__ float geluf(float x) {
    return 0.5f * x * (1.0f + erff(x * 0.70710678118654752f));
}

// fp32 -> bf16 bits, round-to-nearest-even
__device__ __forceinline__ unsigned short f2bf(float f) {
    unsigned int u = __float_as_uint(f);
    u += 0x7fffu + ((u >> 16) & 1u);
    return (unsigned short)(u >> 16);
}

// unpack one half of a packed bf16 pair
__device__ __forceinline__ float bfup(unsigned int u, int hi) {
    return hi ? __uint_as_float(u & 0xffff0000u) : __uint_as_float(u << 16);
}

// ---------------- convert Wr0/1/2 [128x512 f32] -> WrT bf16 [p][n=512][k=128] ----------------
__global__ __launch_bounds__(256) void k_cvt(const float* __restrict__ W0,
                                             const float* __restrict__ W1,
                                             const float* __restrict__ W2,
                                             unsigned short* __restrict__ out) {
    int tid = blockIdx.x * 256 + threadIdx.x;       // 0..196607
    int p = tid >> 16;
    int rem = tid & 65535;
    int n = rem >> 7, k = rem & 127;
    const float* W = p == 0 ? W0 : p == 1 ? W1 : W2;
    out[tid] = f2bf(W[k * HIDD + n]);
}

// ------------- convert Wq/Wk/Wv/Wm [256x512 f32] -> WTn bf16 [sel][n=512][k=256] -------------
__global__ __launch_bounds__(256) void k_cvtn(const float* __restrict__ W0,
                                              const float* __restrict__ W1,
                                              const float* __restrict__ W2,
                                              const float* __restrict__ W3,
                                              unsigned short* __restrict__ out) {
    int tid = blockIdx.x * 256 + threadIdx.x;       // 0..524287
    int sel = tid >> 17;
    int rem = tid & 131071;
    int n = rem >> 8, k = rem & 255;
    const float* W = sel == 0 ? W0 : sel == 1 ? W1 : sel == 2 ? W2 : W3;
    out[tid] = f2bf(W[k * HIDD + n]);
}

// ------- convert Wpre [256x256] -> WpreT bf16 [n=256][k=256]; Wpost [512x256] -> WpostT [n=256][k=512] -------
__global__ __launch_bounds__(256) void k_cvt2(const float* __restrict__ Wpre,
                                              const float* __restrict__ Wpost,
                                              unsigned short* __restrict__ WpreT,
                                              unsigned short* __restrict__ WpostT) {
    int tid = blockIdx.x * 256 + threadIdx.x;       // 0..196607
    if (tid < 65536) {
        int n = tid >> 8, k = tid & 255;
        WpreT[tid] = f2bf(Wpre[k * WID + n]);
    } else {
        int rem = tid - 65536;
        int n = rem >> 9, k = rem & 511;
        WpostT[rem] = f2bf(Wpost[k * WID + n]);
    }
}

// ---------------- pre (MFMA): xxb = bf16(LN(x @ W_pre + b_pre)) ----------------
// 16 rows/block, 4 waves x 64 cols. A packed to bf16 in registers from f32 x.
__global__ __launch_bounds__(256, 4) void k_pre(const float* __restrict__ x,
                                                const unsigned short* __restrict__ WpreT,
                                                const float* __restrict__ bp,
                                                unsigned short* __restrict__ xxb) {
    __shared__ __align__(16) float ot[16 * 260];   // D staging for LN, pitch 260
    int t = threadIdx.x;
    int lane = t & 63, w = t >> 6;
    int l15 = lane & 15, quad = lane >> 4;
    int r0 = blockIdx.x * 16;
    bf16x8 af[8];
    #pragma unroll
    for (int kb = 0; kb < 8; ++kb) {
        int k0 = kb * 32 + quad * 8;
        float a8[8];
        *(float4*)&a8[0] = *(const float4*)&x[(r0 + l15) * WID + k0];
        *(float4*)&a8[4] = *(const float4*)&x[(r0 + l15) * WID + k0 + 4];
        bf16x8 p;
        #pragma unroll
        for (int j = 0; j < 8; ++j) p[j] = (short)f2bf(a8[j]);
        af[kb] = p;
    }
    #pragma unroll
    for (int tb = 0; tb < 4; ++tb) {
        int c = w * 64 + tb * 16 + l15;
        float bias = bp[c];
        f32x4 acc = {bias, bias, bias, bias};
        #pragma unroll
        for (int kb = 0; kb < 8; ++kb) {
            bf16x8 bfr = *(const bf16x8*)&WpreT[c * WID + kb * 32 + quad * 8];
            acc = __builtin_amdgcn_mfma_f32_16x16x32_bf16(af[kb], bfr, acc, 0, 0, 0);
        }
        #pragma unroll
        for (int r = 0; r < 4; ++r)
            ot[(quad * 4 + r) * 260 + c] = acc[r];
    }
    __syncthreads();
    // LN: wave w handles rows w*4 .. w*4+3 (butterfly leaves result in all lanes)
    #pragma unroll
    for (int rr = 0; rr < 4; ++rr) {
        int row = w * 4 + rr;
        float s = 0.f, s2 = 0.f;
        #pragma unroll
        for (int k2 = 0; k2 < 4; ++k2) {
            float v = ot[row * 260 + lane + 64 * k2];
            s += v; s2 += v * v;
        }
        #pragma unroll
        for (int off = 32; off >= 1; off >>= 1) {
            s  += __shfl_xor(s,  off, 64);
            s2 += __shfl_xor(s2, off, 64);
        }
        float m = s * (1.f / WID);
        float rstd = rsqrtf(s2 * (1.f / WID) - m * m + 1e-5f);
        #pragma unroll
        for (int k2 = 0; k2 < 4; ++k2) {
            int c = lane + 64 * k2;
            xxb[(r0 + row) * WID + c] = f2bf((ot[row * 260 + c] - m) * rstd);
        }
    }
}

// ---------------- node QKV + msg0 via MFMA ----------------
// grid (625, 4): 16 rows/block, sel = Q/K/V/M. sel<3 writes pair-packed bf16;
// sel==3 writes gelu() f32 into agg.
__global__ __launch_bounds__(256, 4) void k_qkvm(
    const unsigned short* __restrict__ xxb,   // [N][256] bf16
    const unsigned short* __restrict__ WTn,   // [4][512][256] bf16
    const float* __restrict__ bq, const float* __restrict__ bk,
    const float* __restrict__ bv, const float* __restrict__ bm,
    unsigned short* __restrict__ XQp, unsigned short* __restrict__ XKp,
    unsigned short* __restrict__ XVp, float* __restrict__ AG) {
    int t = threadIdx.x;
    int r0 = blockIdx.x * 16;
    int sel = blockIdx.y;
    const float* bsel = sel == 0 ? bq : sel == 1 ? bk : sel == 2 ? bv : bm;
    const unsigned short* Wp = WTn + sel * (HIDD * WID);
    unsigned short* outp = sel == 0 ? XQp : sel == 1 ? XKp : XVp;
    int lane = t & 63, w = t >> 6;
    int l15 = lane & 15, quad = lane >> 4;
    bf16x8 af[8];
    #pragma unroll
    for (int kb = 0; kb < 8; ++kb)
        af[kb] = *(const bf16x8*)&xxb[(r0 + l15) * WID + kb * 32 + quad * 8];
    #pragma unroll
    for (int tb = 0; tb < 8; ++tb) {
        int c = w * 128 + tb * 16;
        float bias = bsel[c + l15];
        f32x4 acc = {bias, bias, bias, bias};
        #pragma unroll
        for (int kb = 0; kb < 8; ++kb) {
            bf16x8 bfr = *(const bf16x8*)&Wp[(c + l15) * WID + kb * 32 + quad * 8];
            acc = __builtin_amdgcn_mfma_f32_16x16x32_bf16(af[kb], bfr, acc, 0, 0, 0);
        }
        if (sel < 3) {
            int base = ((w * 64 + (tb >> 1) * 16 + l15) << 1) + (tb & 1);
            #pragma unroll
            for (int r = 0; r < 4; ++r) {
                int node = r0 + quad * 4 + r;
                outp[node * 512 + base] = f2bf(acc[r]);
            }
        } else {
            #pragma unroll
            for (int r = 0; r < 4; ++r) {
                int node = r0 + quad * 4 + r;
                AG[node * HIDD + c + l15] = geluf(acc[r]);
            }
        }
    }
}

// ---------------- fused edge kernel: LDS-staged B, wave-owns-tile ----------------
// grid (4, 2500): blockIdx.x = column-group (128 cols = 2 heads), blockIdx.y =
// 64-edge group. Each of the 4 waves owns one 16-edge tile: A-fragments built
// entirely in registers (builder lane == consumer lane). Per part, the 32 KB
// B slice is staged once into LDS (pitch 136 -> bank-balanced ds_read_b128)
// and shared by all 4 waves: B L2 traffic drops 4x and inner-loop latency
// goes from ~200-cyc L2 loads to ~12-cyc LDS reads.
__global__ __launch_bounds__(256, 4) void k_edge(
    const int* __restrict__ eidx, const int* __restrict__ eattr,
    const float* __restrict__ eemb,
    const float* __restrict__ emb0, const float* __restrict__ emb1,
    const float* __restrict__ emb2, const float* __restrict__ emb3,
    const float* __restrict__ i0e, const float* __restrict__ i0,
    const unsigned int* __restrict__ XQp, const unsigned int* __restrict__ XKp,
    const unsigned int* __restrict__ XVp,
    const unsigned short* __restrict__ WrT,   // [3][512][128] bf16
    const float* __restrict__ br0, const float* __restrict__ br1,
    const float* __restrict__ br2,
    float* __restrict__ agg) {
    __shared__ __align__(16) unsigned short Bs[128 * 136];   // 34816 B
    int t = threadIdx.x;
    int lane = t & 63, w = t >> 6;
    int l15 = lane & 15, quad = lane >> 4;
    int cg = blockIdx.x;
    int e0 = blockIdx.y * 64 + w * 16;       // this wave's 16-edge tile

    float ev0 = __expf(i0e[0]), ev1 = __expf(i0e[1]),
          ev2 = __expf(i0e[2]), ev3 = __expf(i0e[3]);
    float rsum = rsqrtf(ev0 + ev1 + ev2 + ev3);
    float xw0 = ev0 * rsum, xw1 = ev1 * rsum, xw2 = ev2 * rsum, xw3 = ev3 * rsum;
    float a_sc = i0[0], a_bi = i0[1];
    float s_e = expf(i0[2]), s_v = expf(i0[3]);
    float c_sc = 0.125f * a_sc;

    // ---- build A fragments in registers (lane: edge l15, k-octet quad*8) ----
    int me = e0 + l15;
    int4 at = *(const int4*)&eattr[me * 4];
    bf16x8 af[4];
    #pragma unroll
    for (int kb = 0; kb < 4; ++kb) {
        int k0 = kb * 32 + quad * 8;
        float t0[8], t1[8], t2[8], t3[8], te[8];
        *(float4*)&t0[0] = *(const float4*)&emb0[at.x * EWID + k0];
        *(float4*)&t0[4] = *(const float4*)&emb0[at.x * EWID + k0 + 4];
        *(float4*)&t1[0] = *(const float4*)&emb1[at.y * EWID + k0];
        *(float4*)&t1[4] = *(const float4*)&emb1[at.y * EWID + k0 + 4];
        *(float4*)&t2[0] = *(const float4*)&emb2[at.z * EWID + k0];
        *(float4*)&t2[4] = *(const float4*)&emb2[at.z * EWID + k0 + 4];
        *(float4*)&t3[0] = *(const float4*)&emb3[at.w * EWID + k0];
        *(float4*)&t3[4] = *(const float4*)&emb3[at.w * EWID + k0 + 4];
        *(float4*)&te[0] = *(const float4*)&eemb[me * EWID + k0];
        *(float4*)&te[4] = *(const float4*)&eemb[me * EWID + k0 + 4];
        bf16x8 p;
        #pragma unroll
        for (int j = 0; j < 8; ++j)
            p[j] = (short)f2bf(0.5f * (xw0 * t0[j] + xw1 * t1[j] + xw2 * t2[j]
                                       + xw3 * t3[j] + te[j]));
        af[kb] = p;
    }

    // ---- gather indices for this lane's edges (quad*4+r) ----
    int ndp[4], nsp[4], nda[4];
    #pragma unroll
    for (int r = 0; r < 4; ++r) {
        int en = e0 + quad * 4 + r;
        int sn = eidx[en], dn = eidx[EE + en];
        ndp[r] = dn * 256 + cg * 64 + l15;
        nsp[r] = sn * 256 + cg * 64 + l15;
        nda[r] = dn * HIDD + cg * 128 + l15;
    }

    // ---- prefetch Q and K node gathers ----
    unsigned int pq[4][4], pk[4][4];
    #pragma unroll
    for (int a = 0; a < 4; ++a)
        #pragma unroll
        for (int r = 0; r < 4; ++r) {
            pq[a][r] = XQp[ndp[r] + a * 16];
            pk[a][r] = XKp[nsp[r] + a * 16];
        }

    // staging pointers: thread t copies col sc, k-half skh (128 B = 8 uint4)
    int sc = t >> 1, skh = (t & 1) * 64;
    const uint4* ssrc = (const uint4*)&WrT[(cg * 128 + sc) * 128 + skh];
    uint4* sdst = (uint4*)&Bs[sc * 136 + skh];

    // ================= part 0: Q =================
    #pragma unroll
    for (int i = 0; i < 8; ++i) sdst[i] = ssrc[i];
    __syncthreads();
    float q[8][4];
    #pragma unroll
    for (int tb = 0; tb < 8; ++tb) {
        int cl = tb * 16 + l15;
        float bias = br0[cg * 128 + cl];
        f32x4 acc = {bias, bias, bias, bias};
        #pragma unroll
        for (int kb = 0; kb < 4; ++kb) {
            bf16x8 bfr = *(const bf16x8*)&Bs[cl * 136 + kb * 32 + quad * 8];
            acc = __builtin_amdgcn_mfma_f32_16x16x32_bf16(af[kb], bfr, acc, 0, 0, 0);
        }
        #pragma unroll
        for (int r = 0; r < 4; ++r)
            q[tb][r] = bfup(pq[tb >> 1][r], tb & 1) + s_e * acc[r];
    }
    // prefetch V gathers (in flight across part 1)
    unsigned int pv[4][4];
    #pragma unroll
    for (int a = 0; a < 4; ++a)
        #pragma unroll
        for (int r = 0; r < 4; ++r) pv[a][r] = XVp[nsp[r] + a * 16];
    __syncthreads();                       // all waves done reading Bs(part0)

    // ================= part 1: K + attention =================
    #pragma unroll
    for (int i = 0; i < 8; ++i) sdst[i] = ssrc[8192 + i];   // +65536 ushorts
    __syncthreads();
    float d0[4] = {0.f, 0.f, 0.f, 0.f}, d1[4] = {0.f, 0.f, 0.f, 0.f};
    #pragma unroll
    for (int tb = 0; tb < 8; ++tb) {
        int cl = tb * 16 + l15;
        float bias = br1[cg * 128 + cl];
        f32x4 acc = {bias, bias, bias, bias};
        #pragma unroll
        for (int kb = 0; kb < 4; ++kb) {
            bf16x8 bfr = *(const bf16x8*)&Bs[cl * 136 + kb * 32 + quad * 8];
            acc = __builtin_amdgcn_mfma_f32_16x16x32_bf16(af[kb], bfr, acc, 0, 0, 0);
        }
        #pragma unroll
        for (int r = 0; r < 4; ++r) {
            float kv = bfup(pk[tb >> 1][r], tb & 1) + s_e * acc[r];
            float pp = q[tb][r] * kv;
            if (tb < 4) d0[r] += pp; else d1[r] += pp;
        }
    }
    float att0[4], att1[4];
    #pragma unroll
    for (int off = 8; off >= 1; off >>= 1) {
        #pragma unroll
        for (int r = 0; r < 4; ++r) {
            d0[r] += __shfl_xor(d0[r], off, 64);
            d1[r] += __shfl_xor(d1[r], off, 64);
        }
    }
    #pragma unroll
    for (int r = 0; r < 4; ++r) {
        att0[r] = expf(d0[r] * c_sc + a_bi);
        att1[r] = expf(d1[r] * c_sc + a_bi);
    }
    __syncthreads();                       // all waves done reading Bs(part1)

    // ================= part 2: V + scatter =================
    #pragma unroll
    for (int i = 0; i < 8; ++i) sdst[i] = ssrc[16384 + i];  // +131072 ushorts
    __syncthreads();
    #pragma unroll
    for (int tb = 0; tb < 8; ++tb) {
        int cl = tb * 16 + l15;
        float bias = br2[cg * 128 + cl];
        f32x4 acc = {bias, bias, bias, bias};
        #pragma unroll
        for (int kb = 0; kb < 4; ++kb) {
            bf16x8 bfr = *(const bf16x8*)&Bs[cl * 136 + kb * 32 + quad * 8];
            acc = __builtin_amdgcn_mfma_f32_16x16x32_bf16(af[kb], bfr, acc, 0, 0, 0);
        }
        #pragma unroll
        for (int r = 0; r < 4; ++r) {
            float v = geluf(bfup(pv[tb >> 1][r], tb & 1) + s_v * acc[r]);
            float m = v * (tb < 4 ? att0[r] : att1[r]);
            atomicAdd(&agg[nda[r] + tb * 16], m);
        }
    }
}

// ---------------- post (MFMA): out = x + agg @ W_post + b_post ----------------
// 16 rows/block, 4 waves x 64 cols. A packed to bf16 in registers from f32 agg.
__global__ __launch_bounds__(256, 4) void k_post(const float* __restrict__ x,
    const float* __restrict__ agg,
    const unsigned short* __restrict__ WpT,   // [256][512] bf16
    const float* __restrict__ bp,
    float* __restrict__ out) {
    int t = threadIdx.x;
    int lane = t & 63, w = t >> 6;
    int l15 = lane & 15, quad = lane >> 4;
    int r0 = blockIdx.x * 16;
    bf16x8 af[16];
    #pragma unroll
    for (int kb = 0; kb < 16; ++kb) {
        int k0 = kb * 32 + quad * 8;
        float a8[8];
        *(float4*)&a8[0] = *(const float4*)&agg[(r0 + l15) * HIDD + k0];
        *(float4*)&a8[4] = *(const float4*)&agg[(r0 + l15) * HIDD + k0 + 4];
        bf16x8 p;
        #pragma unroll
        for (int j = 0; j < 8; ++j) p[j] = (short)f2bf(a8[j]);
        af[kb] = p;
    }
    #pragma unroll
    for (int tb = 0; tb < 4; ++tb) {
        int c = w * 64 + tb * 16 + l15;
        float bias = bp[c];
        f32x4 acc = {bias, bias, bias, bias};
        #pragma unroll
        for (int kb = 0; kb < 16; ++kb) {
            bf16x8 bfr = *(const bf16x8*)&WpT[c * HIDD + kb * 32 + quad * 8];
            acc = __builtin_amdgcn_mfma_f32_16x16x32_bf16(af[kb], bfr, acc, 0, 0, 0);
        }
        #pragma unroll
        for (int r = 0; r < 4; ++r) {
            int row = r0 + quad * 4 + r;
            out[row * WID + c] = x[row * WID + c] + acc[r];
        }
    }
}

extern "C" void kernel_launch(void* const* d_in, const int* in_sizes, int n_in,
                              void* d_out, int out_size, void* d_ws, size_t ws_size,
                              hipStream_t stream) {
    const float* x     = (const float*)d_in[0];
    const int*   eidx  = (const int*)  d_in[1];
    const int*   eattr = (const int*)  d_in[2];
    const float* eemb  = (const float*)d_in[3];
    const float* emb0  = (const float*)d_in[4];
    const float* emb1  = (const float*)d_in[5];
    const float* emb2  = (const float*)d_in[6];
    const float* emb3  = (const float*)d_in[7];
    const float* i0e   = (const float*)d_in[8];
    const float* i0    = (const float*)d_in[9];
    const float* Wpre  = (const float*)d_in[10];
    const float* bpre  = (const float*)d_in[11];
    const float* Wm    = (const float*)d_in[12];
    const float* bm    = (const float*)d_in[13];
    const float* Wq    = (const float*)d_in[14];
    const float* bq    = (const float*)d_in[15];
    const float* Wk    = (const float*)d_in[16];
    const float* bk    = (const float*)d_in[17];
    const float* Wv    = (const float*)d_in[18];
    const float* bv    = (const float*)d_in[19];
    const float* Wr0   = (const float*)d_in[20];
    const float* br0   = (const float*)d_in[21];
    const float* Wr1   = (const float*)d_in[22];
    const float* br1   = (const float*)d_in[23];
    const float* Wr2   = (const float*)d_in[24];
    const float* br2   = (const float*)d_in[25];
    const float* Wpost = (const float*)d_in[26];
    const float* bpost = (const float*)d_in[27];

    float* ws  = (float*)d_ws;
    float* agg = ws;                                           // N*512 f32
    unsigned short* xxb    = (unsigned short*)(ws + 5120000);  // N*256 bf16
    unsigned short* XQp    = (unsigned short*)(ws + 6400000);  // N*512 bf16 packed
    unsigned short* XKp    = (unsigned short*)(ws + 8960000);
    unsigned short* XVp    = (unsigned short*)(ws + 11520000);
    unsigned short* WrT    = (unsigned short*)(ws + 14080000); // 3*512*128
    unsigned short* WTn    = (unsigned short*)(ws + 14178304); // 4*512*256
    unsigned short* WpreT  = (unsigned short*)(ws + 14440448); // 256*256
    unsigned short* WpostT = (unsigned short*)(ws + 14473216); // 256*512
    // total ~58.2 MB

    k_cvt<<<768, 256, 0, stream>>>(Wr0, Wr1, Wr2, WrT);
    k_cvtn<<<2048, 256, 0, stream>>>(Wq, Wk, Wv, Wm, WTn);
    k_cvt2<<<768, 256, 0, stream>>>(Wpre, Wpost, WpreT, WpostT);
    k_pre<<<625, 256, 0, stream>>>(x, WpreT, bpre, xxb);
    k_qkvm<<<dim3(625, 4), 256, 0, stream>>>(xxb, WTn, bq, bk, bv, bm,
                                             XQp, XKp, XVp, agg);
    k_edge<<<dim3(4, 2500), 256, 0, stream>>>(eidx, eattr, eemb,
                                              emb0, emb1, emb2, emb3,
                                              i0e, i0,
                                              (const unsigned int*)XQp,
                                              (const unsigned int*)XKp,
                                              (const unsigned int*)XVp,
                                              WrT, br0, br1, br2, agg);
    k_post<<<625, 256, 0, stream>>>(x, agg, WpostT, bpost, (float*)d_out);
}

// Round 7
// 693.979 us; speedup vs baseline: 4.5207x; 1.0930x over previous
//
#include <hip/hip_runtime.h>
#include <hip/hip_bf16.h>
#include <math.h>

// Problem constants (fixed by the reference)
#define NN   10000   // nodes
#define EE   160000  // edges
#define WID  256     // node width
#define HIDD 512     // hidden
#define EWID 128     // edge embed width

typedef __attribute__((ext_vector_type(8))) short bf16x8;
typedef __attribute__((ext_vector_type(4))) float f32x4;

__device__ __forceinline__ float geluf(float x) {
    return 0.5f * x * (1.0f + erff(x * 0.70710678118654752f));
}

// fp32 -> bf16 bits, round-to-nearest-even
__device__ __forceinline__ unsigned short f2bf(float f) {
    unsigned int u = __float_as_uint(f);
    u += 0x7fffu + ((u >> 16) & 1u);
    return (unsigned short)(u >> 16);
}

// unpack one half of a packed bf16 pair
__device__ __forceinline__ float bfup(unsigned int u, int hi) {
    return hi ? __uint_as_float(u & 0xffff0000u) : __uint_as_float(u << 16);
}

// ---------------- convert Wr0/1/2 [128x512 f32] -> WrT bf16 [p][n=512][k=128] ----------------
__global__ __launch_bounds__(256) void k_cvt(const float* __restrict__ W0,
                                             const float* __restrict__ W1,
                                             const float* __restrict__ W2,
                                             unsigned short* __restrict__ out) {
    int tid = blockIdx.x * 256 + threadIdx.x;       // 0..196607
    int p = tid >> 16;
    int rem = tid & 65535;
    int n = rem >> 7, k = rem & 127;
    const float* W = p == 0 ? W0 : p == 1 ? W1 : W2;
    out[tid] = f2bf(W[k * HIDD + n]);
}

// ------------- convert Wq/Wk/Wv/Wm [256x512 f32] -> WTn bf16 [sel][n=512][k=256] -------------
__global__ __launch_bounds__(256) void k_cvtn(const float* __restrict__ W0,
                                              const float* __restrict__ W1,
                                              const float* __restrict__ W2,
                                              const float* __restrict__ W3,
                                              unsigned short* __restrict__ out) {
    int tid = blockIdx.x * 256 + threadIdx.x;       // 0..524287
    int sel = tid >> 17;
    int rem = tid & 131071;
    int n = rem >> 8, k = rem & 255;
    const float* W = sel == 0 ? W0 : sel == 1 ? W1 : sel == 2 ? W2 : W3;
    out[tid] = f2bf(W[k * HIDD + n]);
}

// ------- convert Wpre [256x256] -> WpreT bf16 [n][k]; Wpost [512x256] -> WpostT [n=256][k=512] -------
__global__ __launch_bounds__(256) void k_cvt2(const float* __restrict__ Wpre,
                                              const float* __restrict__ Wpost,
                                              unsigned short* __restrict__ WpreT,
                                              unsigned short* __restrict__ WpostT) {
    int tid = blockIdx.x * 256 + threadIdx.x;       // 0..196607
    if (tid < 65536) {
        int n = tid >> 8, k = tid & 255;
        WpreT[tid] = f2bf(Wpre[k * WID + n]);
    } else {
        int rem = tid - 65536;
        int n = rem >> 9, k = rem & 511;
        WpostT[rem] = f2bf(Wpost[k * WID + n]);
    }
}

// ---------------- ee build: bf16 A-fragment-ordered edge embeddings ----------------
// eeF layout: fragment chunk c = ((tile*4 + kb)*64 + lane), 8 bf16 each;
// tile = edge>>4, lane = (quad<<4)|l15: edge = tile*16+l15, k = kb*32+quad*8.
// Computed ONCE (was rebuilt 4x inside k_edge).
__global__ __launch_bounds__(256) void k_ee(
    const int* __restrict__ eattr, const float* __restrict__ eemb,
    const float* __restrict__ emb0, const float* __restrict__ emb1,
    const float* __restrict__ emb2, const float* __restrict__ emb3,
    const float* __restrict__ i0e,
    unsigned short* __restrict__ eeF) {
    int c = blockIdx.x * 256 + threadIdx.x;        // 0 .. E*16-1 (2,560,000)
    int lane6 = c & 63;
    int kb = (c >> 6) & 3;
    int tile = c >> 8;
    int edge = tile * 16 + (lane6 & 15);
    int k0 = kb * 32 + (lane6 >> 4) * 8;
    float ev0 = __expf(i0e[0]), ev1 = __expf(i0e[1]),
          ev2 = __expf(i0e[2]), ev3 = __expf(i0e[3]);
    float rsum = rsqrtf(ev0 + ev1 + ev2 + ev3);
    float xw0 = ev0 * rsum, xw1 = ev1 * rsum, xw2 = ev2 * rsum, xw3 = ev3 * rsum;
    int4 at = *(const int4*)&eattr[edge * 4];
    float t0[8], t1[8], t2[8], t3[8], te[8];
    *(float4*)&t0[0] = *(const float4*)&emb0[at.x * EWID + k0];
    *(float4*)&t0[4] = *(const float4*)&emb0[at.x * EWID + k0 + 4];
    *(float4*)&t1[0] = *(const float4*)&emb1[at.y * EWID + k0];
    *(float4*)&t1[4] = *(const float4*)&emb1[at.y * EWID + k0 + 4];
    *(float4*)&t2[0] = *(const float4*)&emb2[at.z * EWID + k0];
    *(float4*)&t2[4] = *(const float4*)&emb2[at.z * EWID + k0 + 4];
    *(float4*)&t3[0] = *(const float4*)&emb3[at.w * EWID + k0];
    *(float4*)&t3[4] = *(const float4*)&emb3[at.w * EWID + k0 + 4];
    *(float4*)&te[0] = *(const float4*)&eemb[edge * EWID + k0];
    *(float4*)&te[4] = *(const float4*)&eemb[edge * EWID + k0 + 4];
    bf16x8 p;
    #pragma unroll
    for (int j = 0; j < 8; ++j)
        p[j] = (short)f2bf(0.5f * (xw0 * t0[j] + xw1 * t1[j] + xw2 * t2[j]
                                   + xw3 * t3[j] + te[j]));
    *(bf16x8*)&eeF[c * 8] = p;
}

// ---------------- pre (MFMA): xxb = bf16(LN(x @ W_pre + b_pre)) ----------------
__global__ __launch_bounds__(256, 4) void k_pre(const float* __restrict__ x,
                                                const unsigned short* __restrict__ WpreT,
                                                const float* __restrict__ bp,
                                                unsigned short* __restrict__ xxb) {
    __shared__ __align__(16) float ot[16 * 260];   // D staging for LN, pitch 260
    int t = threadIdx.x;
    int lane = t & 63, w = t >> 6;
    int l15 = lane & 15, quad = lane >> 4;
    int r0 = blockIdx.x * 16;
    bf16x8 af[8];
    #pragma unroll
    for (int kb = 0; kb < 8; ++kb) {
        int k0 = kb * 32 + quad * 8;
        float a8[8];
        *(float4*)&a8[0] = *(const float4*)&x[(r0 + l15) * WID + k0];
        *(float4*)&a8[4] = *(const float4*)&x[(r0 + l15) * WID + k0 + 4];
        bf16x8 p;
        #pragma unroll
        for (int j = 0; j < 8; ++j) p[j] = (short)f2bf(a8[j]);
        af[kb] = p;
    }
    #pragma unroll
    for (int tb = 0; tb < 4; ++tb) {
        int c = w * 64 + tb * 16 + l15;
        float bias = bp[c];
        f32x4 acc = {bias, bias, bias, bias};
        #pragma unroll
        for (int kb = 0; kb < 8; ++kb) {
            bf16x8 bfr = *(const bf16x8*)&WpreT[c * WID + kb * 32 + quad * 8];
            acc = __builtin_amdgcn_mfma_f32_16x16x32_bf16(af[kb], bfr, acc, 0, 0, 0);
        }
        #pragma unroll
        for (int r = 0; r < 4; ++r)
            ot[(quad * 4 + r) * 260 + c] = acc[r];
    }
    __syncthreads();
    #pragma unroll
    for (int rr = 0; rr < 4; ++rr) {
        int row = w * 4 + rr;
        float s = 0.f, s2 = 0.f;
        #pragma unroll
        for (int k2 = 0; k2 < 4; ++k2) {
            float v = ot[row * 260 + lane + 64 * k2];
            s += v; s2 += v * v;
        }
        #pragma unroll
        for (int off = 32; off >= 1; off >>= 1) {
            s  += __shfl_xor(s,  off, 64);
            s2 += __shfl_xor(s2, off, 64);
        }
        float m = s * (1.f / WID);
        float rstd = rsqrtf(s2 * (1.f / WID) - m * m + 1e-5f);
        #pragma unroll
        for (int k2 = 0; k2 < 4; ++k2) {
            int c = lane + 64 * k2;
            xxb[(r0 + row) * WID + c] = f2bf((ot[row * 260 + c] - m) * rstd);
        }
    }
}

// ---------------- node QKV + msg0 via MFMA, M=32 ----------------
// grid (313, 4): 32 rows/block, sel = Q/K/V/M. Two A-row-sets share each
// B-fragment load (halves B L2 traffic + per-row latency exposure).
__global__ __launch_bounds__(256, 4) void k_qkvm(
    const unsigned short* __restrict__ xxb,   // [N][256] bf16
    const unsigned short* __restrict__ WTn,   // [4][512][256] bf16
    const float* __restrict__ bq, const float* __restrict__ bk,
    const float* __restrict__ bv, const float* __restrict__ bm,
    unsigned short* __restrict__ XQp, unsigned short* __restrict__ XKp,
    unsigned short* __restrict__ XVp, float* __restrict__ AG) {
    int t = threadIdx.x;
    int r0 = blockIdx.x * 32;
    int sel = blockIdx.y;
    const float* bsel = sel == 0 ? bq : sel == 1 ? bk : sel == 2 ? bv : bm;
    const unsigned short* Wp = WTn + sel * (HIDD * WID);
    unsigned short* outp = sel == 0 ? XQp : sel == 1 ? XKp : XVp;
    int lane = t & 63, w = t >> 6;
    int l15 = lane & 15, quad = lane >> 4;
    int rA = min(r0 + l15, NN - 1);
    int rB = min(r0 + 16 + l15, NN - 1);
    bf16x8 af0[8], af1[8];
    #pragma unroll
    for (int kb = 0; kb < 8; ++kb) {
        af0[kb] = *(const bf16x8*)&xxb[rA * WID + kb * 32 + quad * 8];
        af1[kb] = *(const bf16x8*)&xxb[rB * WID + kb * 32 + quad * 8];
    }
    #pragma unroll
    for (int tb = 0; tb < 8; ++tb) {
        int c = w * 128 + tb * 16;
        float bias = bsel[c + l15];
        f32x4 acc0 = {bias, bias, bias, bias};
        f32x4 acc1 = {bias, bias, bias, bias};
        #pragma unroll
        for (int kb = 0; kb < 8; ++kb) {
            bf16x8 bfr = *(const bf16x8*)&Wp[(c + l15) * WID + kb * 32 + quad * 8];
            acc0 = __builtin_amdgcn_mfma_f32_16x16x32_bf16(af0[kb], bfr, acc0, 0, 0, 0);
            acc1 = __builtin_amdgcn_mfma_f32_16x16x32_bf16(af1[kb], bfr, acc1, 0, 0, 0);
        }
        if (sel < 3) {
            int base = ((w * 64 + (tb >> 1) * 16 + l15) << 1) + (tb & 1);
            #pragma unroll
            for (int r = 0; r < 4; ++r) {
                int n0 = r0 + quad * 4 + r;
                int n1 = n0 + 16;
                if (n0 < NN) outp[n0 * 512 + base] = f2bf(acc0[r]);
                if (n1 < NN) outp[n1 * 512 + base] = f2bf(acc1[r]);
            }
        } else {
            #pragma unroll
            for (int r = 0; r < 4; ++r) {
                int n0 = r0 + quad * 4 + r;
                int n1 = n0 + 16;
                if (n0 < NN) AG[n0 * HIDD + c + l15] = geluf(acc0[r]);
                if (n1 < NN) AG[n1 * HIDD + c + l15] = geluf(acc1[r]);
            }
        }
    }
}

// ---------------- fused edge kernel: fragment-order LDS B, precomputed A ----
// grid (4, 2500): blockIdx.x = column-group (128 cols), blockIdx.y = 64-edge
// group; wave w owns edge tile blockIdx.y*4+w. A-fragments are lane-linear
// 16B loads from eeF (precomputed). B staged in fragment order:
// stage write f = i*256+w*64+lane and MFMA read tb*256+kb*64+lane are BOTH
// lane-linear b128 -> zero bank conflicts.
__global__ __launch_bounds__(256, 4) void k_edge(
    const int* __restrict__ eidx,
    const unsigned short* __restrict__ eeF,   // [E/16][4][64][8] bf16
    const float* __restrict__ i0,
    const unsigned int* __restrict__ XQp, const unsigned int* __restrict__ XKp,
    const unsigned int* __restrict__ XVp,
    const unsigned short* __restrict__ WrT,   // [3][512][128] bf16
    const float* __restrict__ br0, const float* __restrict__ br1,
    const float* __restrict__ br2,
    float* __restrict__ agg) {
    __shared__ __align__(16) unsigned short Bs[2048 * 8];   // 32 KB
    int t = threadIdx.x;
    int lane = t & 63, w = t >> 6;
    int l15 = lane & 15, quad = lane >> 4;
    int cg = blockIdx.x;
    int tile = blockIdx.y * 4 + w;
    int e0 = tile * 16;

    float a_sc = i0[0], a_bi = i0[1];
    float s_e = expf(i0[2]), s_v = expf(i0[3]);
    float c_sc = 0.125f * a_sc;

    // ---- A fragments: lane-linear 16B loads, precomputed ----
    bf16x8 af[4];
    #pragma unroll
    for (int kb = 0; kb < 4; ++kb)
        af[kb] = *(const bf16x8*)&eeF[((tile * 4 + kb) * 64 + lane) * 8];

    // ---- gather indices for this lane's edges (quad*4+r) ----
    int ndp[4], nsp[4], nda[4];
    #pragma unroll
    for (int r = 0; r < 4; ++r) {
        int en = e0 + quad * 4 + r;
        int sn = eidx[en], dn = eidx[EE + en];
        ndp[r] = dn * 256 + cg * 64 + l15;
        nsp[r] = sn * 256 + cg * 64 + l15;
        nda[r] = dn * HIDD + cg * 128 + l15;
    }

    // ---- prefetch Q and K node gathers ----
    unsigned int pq[4][4], pk[4][4];
    #pragma unroll
    for (int a = 0; a < 4; ++a)
        #pragma unroll
        for (int r = 0; r < 4; ++r) {
            pq[a][r] = XQp[ndp[r] + a * 16];
            pk[a][r] = XKp[nsp[r] + a * 16];
        }

    // staging: thread (w,lane), iter i copies fragment (tb=i, kb=w,
    // l15=lane&15, quad=lane>>4): src col cg*128+i*16+l15, k w*32+quad*8
    const bf16x8* ssrc0 = (const bf16x8*)&WrT[(cg * 128 + l15) * 128 + w * 32 + quad * 8];
    bf16x8* sdst0 = (bf16x8*)&Bs[(w * 64 + lane) * 8];

    // ================= part 0: Q =================
    #pragma unroll
    for (int i = 0; i < 8; ++i) sdst0[i * 256] = ssrc0[i * 16 * 16];  // i*16 cols * 128/8
    __syncthreads();
    float q[8][4];
    #pragma unroll
    for (int tb = 0; tb < 8; ++tb) {
        float bias = br0[cg * 128 + tb * 16 + l15];
        f32x4 acc = {bias, bias, bias, bias};
        #pragma unroll
        for (int kb = 0; kb < 4; ++kb) {
            bf16x8 bfr = *(const bf16x8*)&Bs[(tb * 256 + kb * 64 + lane) * 8];
            acc = __builtin_amdgcn_mfma_f32_16x16x32_bf16(af[kb], bfr, acc, 0, 0, 0);
        }
        #pragma unroll
        for (int r = 0; r < 4; ++r)
            q[tb][r] = bfup(pq[tb >> 1][r], tb & 1) + s_e * acc[r];
    }
    // prefetch V gathers (in flight across part 1)
    unsigned int pv[4][4];
    #pragma unroll
    for (int a = 0; a < 4; ++a)
        #pragma unroll
        for (int r = 0; r < 4; ++r) pv[a][r] = XVp[nsp[r] + a * 16];
    __syncthreads();

    // ================= part 1: K + attention =================
    #pragma unroll
    for (int i = 0; i < 8; ++i) sdst0[i * 256] = ssrc0[8192 + i * 256];  // +65536 ushorts
    __syncthreads();
    float d0[4] = {0.f, 0.f, 0.f, 0.f}, d1[4] = {0.f, 0.f, 0.f, 0.f};
    #pragma unroll
    for (int tb = 0; tb < 8; ++tb) {
        float bias = br1[cg * 128 + tb * 16 + l15];
        f32x4 acc = {bias, bias, bias, bias};
        #pragma unroll
        for (int kb = 0; kb < 4; ++kb) {
            bf16x8 bfr = *(const bf16x8*)&Bs[(tb * 256 + kb * 64 + lane) * 8];
            acc = __builtin_amdgcn_mfma_f32_16x16x32_bf16(af[kb], bfr, acc, 0, 0, 0);
        }
        #pragma unroll
        for (int r = 0; r < 4; ++r) {
            float kv = bfup(pk[tb >> 1][r], tb & 1) + s_e * acc[r];
            float pp = q[tb][r] * kv;
            if (tb < 4) d0[r] += pp; else d1[r] += pp;
        }
    }
    float att0[4], att1[4];
    #pragma unroll
    for (int off = 8; off >= 1; off >>= 1) {
        #pragma unroll
        for (int r = 0; r < 4; ++r) {
            d0[r] += __shfl_xor(d0[r], off, 64);
            d1[r] += __shfl_xor(d1[r], off, 64);
        }
    }
    #pragma unroll
    for (int r = 0; r < 4; ++r) {
        att0[r] = expf(d0[r] * c_sc + a_bi);
        att1[r] = expf(d1[r] * c_sc + a_bi);
    }
    __syncthreads();

    // ================= part 2: V + scatter =================
    #pragma unroll
    for (int i = 0; i < 8; ++i) sdst0[i * 256] = ssrc0[16384 + i * 256]; // +131072
    __syncthreads();
    #pragma unroll
    for (int tb = 0; tb < 8; ++tb) {
        float bias = br2[cg * 128 + tb * 16 + l15];
        f32x4 acc = {bias, bias, bias, bias};
        #pragma unroll
        for (int kb = 0; kb < 4; ++kb) {
            bf16x8 bfr = *(const bf16x8*)&Bs[(tb * 256 + kb * 64 + lane) * 8];
            acc = __builtin_amdgcn_mfma_f32_16x16x32_bf16(af[kb], bfr, acc, 0, 0, 0);
        }
        #pragma unroll
        for (int r = 0; r < 4; ++r) {
            float v = geluf(bfup(pv[tb >> 1][r], tb & 1) + s_v * acc[r]);
            float m = v * (tb < 4 ? att0[r] : att1[r]);
            atomicAdd(&agg[nda[r] + tb * 16], m);
        }
    }
}

// ---------------- post (MFMA): out = x + agg @ W_post + b_post ----------------
__global__ __launch_bounds__(256, 4) void k_post(const float* __restrict__ x,
    const float* __restrict__ agg,
    const unsigned short* __restrict__ WpT,   // [256][512] bf16
    const float* __restrict__ bp,
    float* __restrict__ out) {
    int t = threadIdx.x;
    int lane = t & 63, w = t >> 6;
    int l15 = lane & 15, quad = lane >> 4;
    int r0 = blockIdx.x * 16;
    bf16x8 af[16];
    #pragma unroll
    for (int kb = 0; kb < 16; ++kb) {
        int k0 = kb * 32 + quad * 8;
        float a8[8];
        *(float4*)&a8[0] = *(const float4*)&agg[(r0 + l15) * HIDD + k0];
        *(float4*)&a8[4] = *(const float4*)&agg[(r0 + l15) * HIDD + k0 + 4];
        bf16x8 p;
        #pragma unroll
        for (int j = 0; j < 8; ++j) p[j] = (short)f2bf(a8[j]);
        af[kb] = p;
    }
    #pragma unroll
    for (int tb = 0; tb < 4; ++tb) {
        int c = w * 64 + tb * 16 + l15;
        float bias = bp[c];
        f32x4 acc = {bias, bias, bias, bias};
        #pragma unroll
        for (int kb = 0; kb < 16; ++kb) {
            bf16x8 bfr = *(const bf16x8*)&WpT[c * HIDD + kb * 32 + quad * 8];
            acc = __builtin_amdgcn_mfma_f32_16x16x32_bf16(af[kb], bfr, acc, 0, 0, 0);
        }
        #pragma unroll
        for (int r = 0; r < 4; ++r) {
            int row = r0 + quad * 4 + r;
            out[row * WID + c] = x[row * WID + c] + acc[r];
        }
    }
}

extern "C" void kernel_launch(void* const* d_in, const int* in_sizes, int n_in,
                              void* d_out, int out_size, void* d_ws, size_t ws_size,
                              hipStream_t stream) {
    const float* x     = (const float*)d_in[0];
    const int*   eidx  = (const int*)  d_in[1];
    const int*   eattr = (const int*)  d_in[2];
    const float* eemb  = (const float*)d_in[3];
    const float* emb0  = (const float*)d_in[4];
    const float* emb1  = (const float*)d_in[5];
    const float* emb2  = (const float*)d_in[6];
    const float* emb3  = (const float*)d_in[7];
    const float* i0e   = (const float*)d_in[8];
    const float* i0    = (const float*)d_in[9];
    const float* Wpre  = (const float*)d_in[10];
    const float* bpre  = (const float*)d_in[11];
    const float* Wm    = (const float*)d_in[12];
    const float* bm    = (const float*)d_in[13];
    const float* Wq    = (const float*)d_in[14];
    const float* bq    = (const float*)d_in[15];
    const float* Wk    = (const float*)d_in[16];
    const float* bk    = (const float*)d_in[17];
    const float* Wv    = (const float*)d_in[18];
    const float* bv    = (const float*)d_in[19];
    const float* Wr0   = (const float*)d_in[20];
    const float* br0   = (const float*)d_in[21];
    const float* Wr1   = (const float*)d_in[22];
    const float* br1   = (const float*)d_in[23];
    const float* Wr2   = (const float*)d_in[24];
    const float* br2   = (const float*)d_in[25];
    const float* Wpost = (const float*)d_in[26];
    const float* bpost = (const float*)d_in[27];

    float* ws  = (float*)d_ws;
    float* agg = ws;                                           // N*512 f32
    unsigned short* xxb    = (unsigned short*)(ws + 5120000);  // N*256 bf16
    unsigned short* XQp    = (unsigned short*)(ws + 6400000);  // N*512 bf16 packed
    unsigned short* XKp    = (unsigned short*)(ws + 8960000);
    unsigned short* XVp    = (unsigned short*)(ws + 11520000);
    unsigned short* WrT    = (unsigned short*)(ws + 14080000); // 3*512*128
    unsigned short* WTn    = (unsigned short*)(ws + 14178304); // 4*512*256
    unsigned short* WpreT  = (unsigned short*)(ws + 14440448); // 256*256
    unsigned short* WpostT = (unsigned short*)(ws + 14473216); // 256*512
    unsigned short* eeF    = (unsigned short*)(ws + 14538752); // E*128 bf16 (41 MB)
    // total ~99.1 MB

    k_cvt<<<768, 256, 0, stream>>>(Wr0, Wr1, Wr2, WrT);
    k_cvtn<<<2048, 256, 0, stream>>>(Wq, Wk, Wv, Wm, WTn);
    k_cvt2<<<768, 256, 0, stream>>>(Wpre, Wpost, WpreT, WpostT);
    k_ee<<<10000, 256, 0, stream>>>(eattr, eemb, emb0, emb1, emb2, emb3, i0e, eeF);
    k_pre<<<625, 256, 0, stream>>>(x, WpreT, bpre, xxb);
    k_qkvm<<<dim3(313, 4), 256, 0, stream>>>(xxb, WTn, bq, bk, bv, bm,
                                             XQp, XKp, XVp, agg);
    k_edge<<<dim3(4, 2500), 256, 0, stream>>>(eidx, eeF, i0,
                                              (const unsigned int*)XQp,
                                              (const unsigned int*)XKp,
                                              (const unsigned int*)XVp,
                                              WrT, br0, br1, br2, agg);
    k_post<<<625, 256, 0, stream>>>(x, agg, WpostT, bpost, (float*)d_out);
}

// Round 8
// 655.463 us; speedup vs baseline: 4.7863x; 1.0588x over previous
//
#include <hip/hip_runtime.h>
#include <hip/hip_bf16.h>
#include <math.h>

// Problem constants (fixed by the reference)
#define NN   10000   // nodes
#define EE   160000  // edges
#define WID  256     // node width
#define HIDD 512     // hidden
#define EWID 128     // edge embed width

typedef __attribute__((ext_vector_type(8))) short bf16x8;
typedef __attribute__((ext_vector_type(4))) float f32x4;

__device__ __forceinline__ float geluf(float x) {
    return 0.5f * x * (1.0f + erff(x * 0.70710678118654752f));
}

// fp32 -> bf16 bits, round-to-nearest-even
__device__ __forceinline__ unsigned short f2bf(float f) {
    unsigned int u = __float_as_uint(f);
    u += 0x7fffu + ((u >> 16) & 1u);
    return (unsigned short)(u >> 16);
}

// unpack one half of a packed bf16 pair
__device__ __forceinline__ float bfup(unsigned int u, int hi) {
    return hi ? __uint_as_float(u & 0xffff0000u) : __uint_as_float(u << 16);
}

// ---------------- all weight conversions in one kernel ----------------
// ranges (block-aligned): [0,196608) WrT; [196608,720896) WTn;
// [720896,786432) WpreT; [786432,917504) WpostT.
__global__ __launch_bounds__(256) void k_cvtall(
    const float* __restrict__ Wr0, const float* __restrict__ Wr1,
    const float* __restrict__ Wr2,
    const float* __restrict__ Wq, const float* __restrict__ Wk,
    const float* __restrict__ Wv, const float* __restrict__ Wm,
    const float* __restrict__ Wpre, const float* __restrict__ Wpost,
    unsigned short* __restrict__ WrT, unsigned short* __restrict__ WTn,
    unsigned short* __restrict__ WpreT, unsigned short* __restrict__ WpostT) {
    int tid = blockIdx.x * 256 + threadIdx.x;
    if (tid < 196608) {
        int p = tid >> 16, rem = tid & 65535;
        int n = rem >> 7, k = rem & 127;
        const float* W = p == 0 ? Wr0 : p == 1 ? Wr1 : Wr2;
        WrT[tid] = f2bf(W[k * HIDD + n]);
    } else if (tid < 720896) {
        int u = tid - 196608;
        int sel = u >> 17, rem = u & 131071;
        int n = rem >> 8, k = rem & 255;
        const float* W = sel == 0 ? Wq : sel == 1 ? Wk : sel == 2 ? Wv : Wm;
        WTn[u] = f2bf(W[k * HIDD + n]);
    } else if (tid < 786432) {
        int u = tid - 720896;
        int n = u >> 8, k = u & 255;
        WpreT[u] = f2bf(Wpre[k * WID + n]);
    } else {
        int u = tid - 786432;
        int n = u >> 9, k = u & 511;
        WpostT[u] = f2bf(Wpost[k * WID + n]);
    }
}

// ---------------- ee build: bf16 A-fragment-ordered edge embeddings ----------------
// eeF layout: fragment chunk c = ((tile*4 + kb)*64 + lane), 8 bf16 each;
// edge = tile*16 + (lane&15), k = kb*32 + (lane>>4)*8.
__global__ __launch_bounds__(256) void k_ee(
    const int* __restrict__ eattr, const float* __restrict__ eemb,
    const float* __restrict__ emb0, const float* __restrict__ emb1,
    const float* __restrict__ emb2, const float* __restrict__ emb3,
    const float* __restrict__ i0e,
    unsigned short* __restrict__ eeF) {
    int c = blockIdx.x * 256 + threadIdx.x;        // 0 .. E*16-1
    int lane6 = c & 63;
    int kb = (c >> 6) & 3;
    int tile = c >> 8;
    int edge = tile * 16 + (lane6 & 15);
    int k0 = kb * 32 + (lane6 >> 4) * 8;
    float ev0 = __expf(i0e[0]), ev1 = __expf(i0e[1]),
          ev2 = __expf(i0e[2]), ev3 = __expf(i0e[3]);
    float rsum = rsqrtf(ev0 + ev1 + ev2 + ev3);
    float xw0 = ev0 * rsum, xw1 = ev1 * rsum, xw2 = ev2 * rsum, xw3 = ev3 * rsum;
    int4 at = *(const int4*)&eattr[edge * 4];
    float t0[8], t1[8], t2[8], t3[8], te[8];
    *(float4*)&t0[0] = *(const float4*)&emb0[at.x * EWID + k0];
    *(float4*)&t0[4] = *(const float4*)&emb0[at.x * EWID + k0 + 4];
    *(float4*)&t1[0] = *(const float4*)&emb1[at.y * EWID + k0];
    *(float4*)&t1[4] = *(const float4*)&emb1[at.y * EWID + k0 + 4];
    *(float4*)&t2[0] = *(const float4*)&emb2[at.z * EWID + k0];
    *(float4*)&t2[4] = *(const float4*)&emb2[at.z * EWID + k0 + 4];
    *(float4*)&t3[0] = *(const float4*)&emb3[at.w * EWID + k0];
    *(float4*)&t3[4] = *(const float4*)&emb3[at.w * EWID + k0 + 4];
    *(float4*)&te[0] = *(const float4*)&eemb[edge * EWID + k0];
    *(float4*)&te[4] = *(const float4*)&eemb[edge * EWID + k0 + 4];
    bf16x8 p;
    #pragma unroll
    for (int j = 0; j < 8; ++j)
        p[j] = (short)f2bf(0.5f * (xw0 * t0[j] + xw1 * t1[j] + xw2 * t2[j]
                                   + xw3 * t3[j] + te[j]));
    *(bf16x8*)&eeF[c * 8] = p;
}

// ---------------- pre (MFMA): xxb = bf16(LN(x @ W_pre + b_pre)) ----------------
__global__ __launch_bounds__(256, 4) void k_pre(const float* __restrict__ x,
                                                const unsigned short* __restrict__ WpreT,
                                                const float* __restrict__ bp,
                                                unsigned short* __restrict__ xxb) {
    __shared__ __align__(16) float ot[16 * 260];   // D staging for LN, pitch 260
    int t = threadIdx.x;
    int lane = t & 63, w = t >> 6;
    int l15 = lane & 15, quad = lane >> 4;
    int r0 = blockIdx.x * 16;
    bf16x8 af[8];
    #pragma unroll
    for (int kb = 0; kb < 8; ++kb) {
        int k0 = kb * 32 + quad * 8;
        float a8[8];
        *(float4*)&a8[0] = *(const float4*)&x[(r0 + l15) * WID + k0];
        *(float4*)&a8[4] = *(const float4*)&x[(r0 + l15) * WID + k0 + 4];
        bf16x8 p;
        #pragma unroll
        for (int j = 0; j < 8; ++j) p[j] = (short)f2bf(a8[j]);
        af[kb] = p;
    }
    #pragma unroll
    for (int tb = 0; tb < 4; ++tb) {
        int c = w * 64 + tb * 16 + l15;
        float bias = bp[c];
        f32x4 acc = {bias, bias, bias, bias};
        #pragma unroll
        for (int kb = 0; kb < 8; ++kb) {
            bf16x8 bfr = *(const bf16x8*)&WpreT[c * WID + kb * 32 + quad * 8];
            acc = __builtin_amdgcn_mfma_f32_16x16x32_bf16(af[kb], bfr, acc, 0, 0, 0);
        }
        #pragma unroll
        for (int r = 0; r < 4; ++r)
            ot[(quad * 4 + r) * 260 + c] = acc[r];
    }
    __syncthreads();
    #pragma unroll
    for (int rr = 0; rr < 4; ++rr) {
        int row = w * 4 + rr;
        float s = 0.f, s2 = 0.f;
        #pragma unroll
        for (int k2 = 0; k2 < 4; ++k2) {
            float v = ot[row * 260 + lane + 64 * k2];
            s += v; s2 += v * v;
        }
        #pragma unroll
        for (int off = 32; off >= 1; off >>= 1) {
            s  += __shfl_xor(s,  off, 64);
            s2 += __shfl_xor(s2, off, 64);
        }
        float m = s * (1.f / WID);
        float rstd = rsqrtf(s2 * (1.f / WID) - m * m + 1e-5f);
        #pragma unroll
        for (int k2 = 0; k2 < 4; ++k2) {
            int c = lane + 64 * k2;
            xxb[(r0 + row) * WID + c] = f2bf((ot[row * 260 + c] - m) * rstd);
        }
    }
}

// ---------------- node QKV + msg0 via MFMA, M=32 ----------------
__global__ __launch_bounds__(256, 4) void k_qkvm(
    const unsigned short* __restrict__ xxb,   // [N][256] bf16
    const unsigned short* __restrict__ WTn,   // [4][512][256] bf16
    const float* __restrict__ bq, const float* __restrict__ bk,
    const float* __restrict__ bv, const float* __restrict__ bm,
    unsigned short* __restrict__ XQp, unsigned short* __restrict__ XKp,
    unsigned short* __restrict__ XVp, float* __restrict__ AG) {
    int t = threadIdx.x;
    int r0 = blockIdx.x * 32;
    int sel = blockIdx.y;
    const float* bsel = sel == 0 ? bq : sel == 1 ? bk : sel == 2 ? bv : bm;
    const unsigned short* Wp = WTn + sel * (HIDD * WID);
    unsigned short* outp = sel == 0 ? XQp : sel == 1 ? XKp : XVp;
    int lane = t & 63, w = t >> 6;
    int l15 = lane & 15, quad = lane >> 4;
    int rA = min(r0 + l15, NN - 1);
    int rB = min(r0 + 16 + l15, NN - 1);
    bf16x8 af0[8], af1[8];
    #pragma unroll
    for (int kb = 0; kb < 8; ++kb) {
        af0[kb] = *(const bf16x8*)&xxb[rA * WID + kb * 32 + quad * 8];
        af1[kb] = *(const bf16x8*)&xxb[rB * WID + kb * 32 + quad * 8];
    }
    #pragma unroll
    for (int tb = 0; tb < 8; ++tb) {
        int c = w * 128 + tb * 16;
        float bias = bsel[c + l15];
        f32x4 acc0 = {bias, bias, bias, bias};
        f32x4 acc1 = {bias, bias, bias, bias};
        #pragma unroll
        for (int kb = 0; kb < 8; ++kb) {
            bf16x8 bfr = *(const bf16x8*)&Wp[(c + l15) * WID + kb * 32 + quad * 8];
            acc0 = __builtin_amdgcn_mfma_f32_16x16x32_bf16(af0[kb], bfr, acc0, 0, 0, 0);
            acc1 = __builtin_amdgcn_mfma_f32_16x16x32_bf16(af1[kb], bfr, acc1, 0, 0, 0);
        }
        if (sel < 3) {
            int base = ((w * 64 + (tb >> 1) * 16 + l15) << 1) + (tb & 1);
            #pragma unroll
            for (int r = 0; r < 4; ++r) {
                int n0 = r0 + quad * 4 + r;
                int n1 = n0 + 16;
                if (n0 < NN) outp[n0 * 512 + base] = f2bf(acc0[r]);
                if (n1 < NN) outp[n1 * 512 + base] = f2bf(acc1[r]);
            }
        } else {
            #pragma unroll
            for (int r = 0; r < 4; ++r) {
                int n0 = r0 + quad * 4 + r;
                int n1 = n0 + 16;
                if (n0 < NN) AG[n0 * HIDD + c + l15] = geluf(acc0[r]);
                if (n1 < NN) AG[n1 * HIDD + c + l15] = geluf(acc1[r]);
            }
        }
    }
}

// ---------------- fused edge kernel: 64-col groups, 16 KB LDS, high occupancy ----
// grid (8, 2500): blockIdx.x = cg (64 cols == exactly one head), blockIdx.y =
// 64-edge group; wave w owns edge tile y*4+w. A-fragments lane-linear from eeF.
// B staged in fragment order (both staging writes and MFMA reads lane-linear
// b128 -> zero conflicts). 16 KB LDS + small state -> 6 blocks/CU (75% occ).
// Attention head == the wave's 64 cols: dot = in-lane sum over tb + 16-lane
// butterfly.
__global__ __launch_bounds__(256, 6) void k_edge(
    const int* __restrict__ eidx,
    const unsigned short* __restrict__ eeF,   // [E/16][4][64][8] bf16
    const float* __restrict__ i0,
    const unsigned int* __restrict__ XQp, const unsigned int* __restrict__ XKp,
    const unsigned int* __restrict__ XVp,
    const unsigned short* __restrict__ WrT,   // [3][512][128] bf16
    const float* __restrict__ br0, const float* __restrict__ br1,
    const float* __restrict__ br2,
    float* __restrict__ agg) {
    __shared__ __align__(16) unsigned short Bs[1024 * 8];   // 16 KB
    int t = threadIdx.x;
    int lane = t & 63, w = t >> 6;
    int l15 = lane & 15, quad = lane >> 4;
    int cg = blockIdx.x;                     // 64-col group
    int tile = blockIdx.y * 4 + w;
    int e0 = tile * 16;

    float a_sc = i0[0], a_bi = i0[1];
    float s_e = expf(i0[2]), s_v = expf(i0[3]);
    float c_sc = 0.125f * a_sc;

    // ---- A fragments: lane-linear 16B loads, precomputed ----
    bf16x8 af[4];
    #pragma unroll
    for (int kb = 0; kb < 4; ++kb)
        af[kb] = *(const bf16x8*)&eeF[((tile * 4 + kb) * 64 + lane) * 8];

    // ---- edge endpoints for this lane's edges (quad*4+r) ----
    int dn[4], sn[4];
    #pragma unroll
    for (int r = 0; r < 4; ++r) {
        int en = e0 + quad * 4 + r;
        sn[r] = eidx[en];
        dn[r] = eidx[EE + en];
    }

    // ---- prefetch Q and K node gathers (2 dwords per edge each) ----
    unsigned int pq[2][4], pk[2][4];
    #pragma unroll
    for (int a = 0; a < 2; ++a)
        #pragma unroll
        for (int r = 0; r < 4; ++r) {
            pq[a][r] = XQp[dn[r] * 256 + cg * 32 + l15 + a * 16];
            pk[a][r] = XKp[sn[r] * 256 + cg * 32 + l15 + a * 16];
        }

    // staging: thread t copies fragments f = i*256+t (tb=i, kb=w, lane)
    int s_off = (cg * 64 + l15) * 128 + w * 32 + quad * 8;  // ushort offset
    bf16x8* sdst = (bf16x8*)Bs + t;
    const bf16x8* bsr = (const bf16x8*)Bs;

    // ================= part 0: Q =================
    #pragma unroll
    for (int i = 0; i < 4; ++i)
        sdst[i * 256] = *(const bf16x8*)&WrT[s_off + i * 2048];
    __syncthreads();
    float q[4][4];
    #pragma unroll
    for (int tb = 0; tb < 4; ++tb) {
        float bias = br0[cg * 64 + tb * 16 + l15];
        f32x4 acc = {bias, bias, bias, bias};
        #pragma unroll
        for (int kb = 0; kb < 4; ++kb)
            acc = __builtin_amdgcn_mfma_f32_16x16x32_bf16(af[kb], bsr[tb * 256 + kb * 64 + lane], acc, 0, 0, 0);
        #pragma unroll
        for (int r = 0; r < 4; ++r)
            q[tb][r] = bfup(pq[tb >> 1][r], tb & 1) + s_e * acc[r];
    }
    // prefetch V gathers (in flight across part 1)
    unsigned int pv[2][4];
    #pragma unroll
    for (int a = 0; a < 2; ++a)
        #pragma unroll
        for (int r = 0; r < 4; ++r)
            pv[a][r] = XVp[sn[r] * 256 + cg * 32 + l15 + a * 16];
    __syncthreads();

    // ================= part 1: K + attention =================
    #pragma unroll
    for (int i = 0; i < 4; ++i)
        sdst[i * 256] = *(const bf16x8*)&WrT[65536 + s_off + i * 2048];
    __syncthreads();
    float d[4] = {0.f, 0.f, 0.f, 0.f};
    #pragma unroll
    for (int tb = 0; tb < 4; ++tb) {
        float bias = br1[cg * 64 + tb * 16 + l15];
        f32x4 acc = {bias, bias, bias, bias};
        #pragma unroll
        for (int kb = 0; kb < 4; ++kb)
            acc = __builtin_amdgcn_mfma_f32_16x16x32_bf16(af[kb], bsr[tb * 256 + kb * 64 + lane], acc, 0, 0, 0);
        #pragma unroll
        for (int r = 0; r < 4; ++r) {
            float kv = bfup(pk[tb >> 1][r], tb & 1) + s_e * acc[r];
            d[r] += q[tb][r] * kv;
        }
    }
    float att[4];
    #pragma unroll
    for (int off = 8; off >= 1; off >>= 1)
        #pragma unroll
        for (int r = 0; r < 4; ++r)
            d[r] += __shfl_xor(d[r], off, 64);
    #pragma unroll
    for (int r = 0; r < 4; ++r)
        att[r] = expf(d[r] * c_sc + a_bi);
    __syncthreads();

    // ================= part 2: V + scatter =================
    #pragma unroll
    for (int i = 0; i < 4; ++i)
        sdst[i * 256] = *(const bf16x8*)&WrT[131072 + s_off + i * 2048];
    __syncthreads();
    #pragma unroll
    for (int tb = 0; tb < 4; ++tb) {
        float bias = br2[cg * 64 + tb * 16 + l15];
        f32x4 acc = {bias, bias, bias, bias};
        #pragma unroll
        for (int kb = 0; kb < 4; ++kb)
            acc = __builtin_amdgcn_mfma_f32_16x16x32_bf16(af[kb], bsr[tb * 256 + kb * 64 + lane], acc, 0, 0, 0);
        #pragma unroll
        for (int r = 0; r < 4; ++r) {
            float v = geluf(bfup(pv[tb >> 1][r], tb & 1) + s_v * acc[r]);
            atomicAdd(&agg[dn[r] * HIDD + cg * 64 + tb * 16 + l15], v * att[r]);
        }
    }
}

// ---------------- post (MFMA): out = x + agg @ W_post + b_post ----------------
__global__ __launch_bounds__(256, 4) void k_post(const float* __restrict__ x,
    const float* __restrict__ agg,
    const unsigned short* __restrict__ WpT,   // [256][512] bf16
    const float* __restrict__ bp,
    float* __restrict__ out) {
    int t = threadIdx.x;
    int lane = t & 63, w = t >> 6;
    int l15 = lane & 15, quad = lane >> 4;
    int r0 = blockIdx.x * 16;
    bf16x8 af[16];
    #pragma unroll
    for (int kb = 0; kb < 16; ++kb) {
        int k0 = kb * 32 + quad * 8;
        float a8[8];
        *(float4*)&a8[0] = *(const float4*)&agg[(r0 + l15) * HIDD + k0];
        *(float4*)&a8[4] = *(const float4*)&agg[(r0 + l15) * HIDD + k0 + 4];
        bf16x8 p;
        #pragma unroll
        for (int j = 0; j < 8; ++j) p[j] = (short)f2bf(a8[j]);
        af[kb] = p;
    }
    #pragma unroll
    for (int tb = 0; tb < 4; ++tb) {
        int c = w * 64 + tb * 16 + l15;
        float bias = bp[c];
        f32x4 acc = {bias, bias, bias, bias};
        #pragma unroll
        for (int kb = 0; kb < 16; ++kb) {
            bf16x8 bfr = *(const bf16x8*)&WpT[c * HIDD + kb * 32 + quad * 8];
            acc = __builtin_amdgcn_mfma_f32_16x16x32_bf16(af[kb], bfr, acc, 0, 0, 0);
        }
        #pragma unroll
        for (int r = 0; r < 4; ++r) {
            int row = r0 + quad * 4 + r;
            out[row * WID + c] = x[row * WID + c] + acc[r];
        }
    }
}

extern "C" void kernel_launch(void* const* d_in, const int* in_sizes, int n_in,
                              void* d_out, int out_size, void* d_ws, size_t ws_size,
                              hipStream_t stream) {
    const float* x     = (const float*)d_in[0];
    const int*   eidx  = (const int*)  d_in[1];
    const int*   eattr = (const int*)  d_in[2];
    const float* eemb  = (const float*)d_in[3];
    const float* emb0  = (const float*)d_in[4];
    const float* emb1  = (const float*)d_in[5];
    const float* emb2  = (const float*)d_in[6];
    const float* emb3  = (const float*)d_in[7];
    const float* i0e   = (const float*)d_in[8];
    const float* i0    = (const float*)d_in[9];
    const float* Wpre  = (const float*)d_in[10];
    const float* bpre  = (const float*)d_in[11];
    const float* Wm    = (const float*)d_in[12];
    const float* bm    = (const float*)d_in[13];
    const float* Wq    = (const float*)d_in[14];
    const float* bq    = (const float*)d_in[15];
    const float* Wk    = (const float*)d_in[16];
    const float* bk    = (const float*)d_in[17];
    const float* Wv    = (const float*)d_in[18];
    const float* bv    = (const float*)d_in[19];
    const float* Wr0   = (const float*)d_in[20];
    const float* br0   = (const float*)d_in[21];
    const float* Wr1   = (const float*)d_in[22];
    const float* br1   = (const float*)d_in[23];
    const float* Wr2   = (const float*)d_in[24];
    const float* br2   = (const float*)d_in[25];
    const float* Wpost = (const float*)d_in[26];
    const float* bpost = (const float*)d_in[27];

    float* ws  = (float*)d_ws;
    float* agg = ws;                                           // N*512 f32
    unsigned short* xxb    = (unsigned short*)(ws + 5120000);  // N*256 bf16
    unsigned short* XQp    = (unsigned short*)(ws + 6400000);  // N*512 bf16 packed
    unsigned short* XKp    = (unsigned short*)(ws + 8960000);
    unsigned short* XVp    = (unsigned short*)(ws + 11520000);
    unsigned short* WrT    = (unsigned short*)(ws + 14080000); // 3*512*128
    unsigned short* WTn    = (unsigned short*)(ws + 14178304); // 4*512*256
    unsigned short* WpreT  = (unsigned short*)(ws + 14440448); // 256*256
    unsigned short* WpostT = (unsigned short*)(ws + 14473216); // 256*512
    unsigned short* eeF    = (unsigned short*)(ws + 14538752); // E*128 bf16 (41 MB)
    // total ~99.1 MB

    k_cvtall<<<3584, 256, 0, stream>>>(Wr0, Wr1, Wr2, Wq, Wk, Wv, Wm, Wpre, Wpost,
                                       WrT, WTn, WpreT, WpostT);
    k_ee<<<10000, 256, 0, stream>>>(eattr, eemb, emb0, emb1, emb2, emb3, i0e, eeF);
    k_pre<<<625, 256, 0, stream>>>(x, WpreT, bpre, xxb);
    k_qkvm<<<dim3(313, 4), 256, 0, stream>>>(xxb, WTn, bq, bk, bv, bm,
                                             XQp, XKp, XVp, agg);
    k_edge<<<dim3(8, 2500), 256, 0, stream>>>(eidx, eeF, i0,
                                              (const unsigned int*)XQp,
                                              (const unsigned int*)XKp,
                                              (const unsigned int*)XVp,
                                              WrT, br0, br1, br2, agg);
    k_post<<<625, 256, 0, stream>>>(x, agg, WpostT, bpost, (float*)d_out);
}